// Round 2
// baseline (1033.782 us; speedup 1.0000x reference)
//
#include <hip/hip_runtime.h>
#include <cstdint>

typedef _Float16 f16;
typedef __attribute__((ext_vector_type(8))) _Float16 f16x8;
typedef __attribute__((ext_vector_type(4))) float f32x4;

constexpr int Bc  = 4;
constexpr int Sc  = 2048;
constexpr int Dc  = 2048;
constexpr int Hc  = 16;
constexpr int HDc = 128;

// ---------------- fused fp32 -> fp16 cast (all 5 tensors, 1 launch) ----------------
__global__ void cast_all_kernel(const float* __restrict__ x,  const float* __restrict__ wq,
                                const float* __restrict__ wk, const float* __restrict__ wv,
                                const float* __restrict__ wo,
                                f16* __restrict__ xh,  f16* __restrict__ wqh,
                                f16* __restrict__ wkh, f16* __restrict__ wvh,
                                f16* __restrict__ woh)
{
    long bid = blockIdx.x;
    const float* src; f16* dst; long off;
    if (bid < 8192)       { src = x;  dst = xh;  off = bid * 2048; }
    else {
        int r = (int)((bid - 8192) >> 11);
        off = ((bid - 8192) & 2047) * 2048;
        switch (r) {
            case 0:  src = wq; dst = wqh; break;
            case 1:  src = wk; dst = wkh; break;
            case 2:  src = wv; dst = wvh; break;
            default: src = wo; dst = woh; break;
        }
    }
    long i = off + (long)threadIdx.x * 8;
    float4 a = *(const float4*)(src + i);
    float4 b = *(const float4*)(src + i + 4);
    f16x8 o = { (f16)a.x, (f16)a.y, (f16)a.z, (f16)a.w,
                (f16)b.x, (f16)b.y, (f16)b.z, (f16)b.w };
    *(f16x8*)(dst + i) = o;
}

// ---------------- async global->LDS 16B/lane ----------------
__device__ __forceinline__ void async_cp16(const f16* g, f16* l)
{
    __builtin_amdgcn_global_load_lds(
        (__attribute__((address_space(1))) void*)(g),
        (__attribute__((address_space(3))) void*)(l), 16, 0, 0);
}

// ---------------- GEMM: C[m,n] = sum_k A[m,k] * W[n,k] ----------------
// 256x256 tile, 512 threads (8 waves, 2M x 4N), BK=32, ring of 4 LDS K-slots.
// R2 change: intra-tile lockstep barriers REMOVED (ring-4 makes them unneeded:
// slot kt&3 is re-staged 2 iterations / >=2 tile-end barriers after its last
// read, and skew is bounded <1 iter by the single tile-end barrier). Waves can
// now slip phases -> one wave's ds_reads overlap the other's MFMAs on the same
// SIMD. Per-wave lgkmcnt(0)+sched_barrier(0) before each MFMA cluster kept
// (rule #18). Counted vmcnt(4) at tile end only (t+1 landed, t+2 in flight).
template<typename OUT_T>
__global__ __launch_bounds__(512, 2) void gemm_bt8(
    const f16* __restrict__ A, const f16* __restrict__ W,
    OUT_T* __restrict__ C, int M, int N, int K)
{
    __shared__ alignas(16) f16 As[4][8192];   // [slot][256 rows x 32 cols]
    __shared__ alignas(16) f16 Bs[4][8192];

    const int tid  = threadIdx.x;
    const int wave = tid >> 6, lane = tid & 63;
    const int l16  = lane & 15, quad = lane >> 4;
    const int wm   = wave >> 2, wn = wave & 3;

    // XCD-bijective block swizzle (nwg is a multiple of 8 here: 32x8=256)
    const int nwg = (int)gridDim.x;
    int bid = (int)blockIdx.x;
    int wg  = ((nwg & 7) == 0) ? ((bid & 7) * (nwg >> 3) + (bid >> 3)) : bid;
    const int ntile = N >> 8;
    const int mt = wg / ntile, nt = wg % ntile;
    const int m0 = mt << 8, n0 = nt << 8;

    // ---- staging addresses (thread t covers phys row=t>>2, chunk=t&3) ----
    const int  prow = tid >> 2;                               // 0..127
    const int  lch  = (((tid & 3) ^ ((prow >> 1) & 3)) << 3); // logical f16 col
    const f16* Asrc = A + (long)(m0 + prow) * K + lch;
    const f16* Bsrc = W + (long)(n0 + prow) * K + lch;
    const long rsk  = (long)K << 7;           // +128 rows
    const int  dst0 = wave << 9;              // wave-uniform LDS base (f16)

    const int nkt = K >> 5;

    auto stA = [&](int kt) {
        const f16* g = Asrc + ((long)kt << 5);
        int s = kt & 3;
        async_cp16(g,       &As[s][dst0]);
        async_cp16(g + rsk, &As[s][4096 + dst0]);
    };
    auto stB = [&](int kt) {
        const f16* g = Bsrc + ((long)kt << 5);
        int s = kt & 3;
        async_cp16(g,       &Bs[s][dst0]);
        async_cp16(g + rsk, &Bs[s][4096 + dst0]);
    };

    // ---- fragment read addressing (swizzled chunk is lane-constant) ----
    const int coff = ((quad ^ ((l16 >> 1) & 3)) << 3);
    const int arow = wm * 128 + l16;          // + i*16
    const int brow = wn * 64  + l16;          // + j*16

    f32x4 acc[8][4];
#pragma unroll
    for (int i = 0; i < 8; i++)
#pragma unroll
        for (int j = 0; j < 4; j++) acc[i][j] = (f32x4){0.f, 0.f, 0.f, 0.f};

    // ---- prologue: stage tiles 0 and 1 ----
    stA(0); stB(0);
    if (nkt > 1) {
        stA(1); stB(1);
        asm volatile("s_waitcnt vmcnt(4)" ::: "memory");
    } else {
        asm volatile("s_waitcnt vmcnt(0)" ::: "memory");
    }
    __builtin_amdgcn_s_barrier();
    __builtin_amdgcn_sched_barrier(0);

    for (int kt = 0; kt < nkt; ++kt) {
        const int s = kt & 3;
        const f16* as = &As[s][(long)arow * 32 + coff];
        const f16* bs = &Bs[s][(long)brow * 32 + coff];

        // ---- phase 1: B all + A low-half, stage A(t+2), MFMA quadrant 0 ----
        f16x8 bfr[4], afr[4];
#pragma unroll
        for (int j = 0; j < 4; ++j) bfr[j] = *(const f16x8*)(bs + j * 512);
#pragma unroll
        for (int i = 0; i < 4; ++i) afr[i] = *(const f16x8*)(as + i * 512);
        if (kt + 2 < nkt) stA(kt + 2);
        asm volatile("s_waitcnt lgkmcnt(0)" ::: "memory");
        __builtin_amdgcn_sched_barrier(0);
        __builtin_amdgcn_s_setprio(1);
#pragma unroll
        for (int i = 0; i < 4; ++i)
#pragma unroll
            for (int j = 0; j < 4; ++j)
                acc[i][j] = __builtin_amdgcn_mfma_f32_16x16x32_f16(afr[i], bfr[j], acc[i][j], 0, 0, 0);
        __builtin_amdgcn_s_setprio(0);

        // ---- phase 2: A high-half, stage B(t+2), MFMA quadrant 1 ----
        f16x8 afr2[4];
#pragma unroll
        for (int i = 0; i < 4; ++i) afr2[i] = *(const f16x8*)(as + (i + 4) * 512);
        if (kt + 2 < nkt) stB(kt + 2);
        asm volatile("s_waitcnt lgkmcnt(0)" ::: "memory");
        __builtin_amdgcn_sched_barrier(0);
        __builtin_amdgcn_s_setprio(1);
#pragma unroll
        for (int i = 0; i < 4; ++i)
#pragma unroll
            for (int j = 0; j < 4; ++j)
                acc[i + 4][j] = __builtin_amdgcn_mfma_f32_16x16x32_f16(afr2[i], bfr[j], acc[i + 4][j], 0, 0, 0);
        __builtin_amdgcn_s_setprio(0);

        // ---- tile boundary: counted wait (tile t+1 landed, t+2 in flight) ----
        if (kt + 2 < nkt) asm volatile("s_waitcnt vmcnt(4)" ::: "memory");
        else              asm volatile("s_waitcnt vmcnt(0)" ::: "memory");
        __builtin_amdgcn_s_barrier();
        __builtin_amdgcn_sched_barrier(0);
    }

    // ---- epilogue ----
#pragma unroll
    for (int i = 0; i < 8; ++i) {
        int row = m0 + wm * 128 + i * 16 + quad * 4;
#pragma unroll
        for (int j = 0; j < 4; ++j) {
            int col = n0 + wn * 64 + j * 16 + l16;
#pragma unroll
            for (int r = 0; r < 4; ++r)
                C[(long)(row + r) * N + col] = (OUT_T)acc[i][j][r];
        }
    }
}

// ---------------- RoPE (in-place on fp16 Q and K) ----------------
__global__ void rope_kernel(f16* __restrict__ Q, f16* __restrict__ K,
                            const int* __restrict__ pos, long npairs)
{
    long t = (long)blockIdx.x * blockDim.x + threadIdx.x;
    if (t >= 2 * npairs) return;
    f16* P = Q;
    long p = t;
    if (p >= npairs) { P = K; p -= npairs; }
    int  i    = (int)(p & 63);
    long rest = p >> 6;
    int  h    = (int)(rest & (Hc - 1));
    long row  = rest >> 4;
    int  s    = (int)(row & (Sc - 1));

    float inv = expf(-(float)i * (9.210340371976184f / 64.0f));
    float ang = (float)pos[s] * inv;
    float sn, cs;
    sincosf(ang, &sn, &cs);

    long idx = row * Dc + (long)h * HDc + 2 * i;
    unsigned int u = *(const unsigned int*)(P + idx);
    float x1 = (float)((const f16*)&u)[0];
    float x2 = (float)((const f16*)&u)[1];
    f16 o[2] = { (f16)(x1 * cs - x2 * sn), (f16)(x1 * sn + x2 * cs) };
    *(unsigned int*)(P + idx) = *(const unsigned int*)o;
}

// ---------------- Flash attention v5 (causal) ----------------
// R2 change: Kt single-buffered (LDS 64K -> 48K => 3 blocks/CU, was 2).
// Counters showed latency-bound: MfmaUtil 17% (= causal FLOP floor),
// Occupancy 13.6%/25% ceiling, all pipes <25% busy -> raise concurrency.
// New per-tile schedule (3 __syncthreads):
//   A: (drains vmcnt) K[kt] in Kt, V[kt] in vreg -> write Vt
//   B: Vt visible -> QK^T (reads Kt)
//   C: all Kt reads retired -> issue K-DMA[kt+1] into Kt + load_v(kt+1),
//      both hidden under softmax+PV; waited at next A.
__device__ __forceinline__ int swz(int row, int col, int ldshift) {
    return (row << ldshift) + (((((col >> 3) ^ ((row >> 1) & 7)) << 3) | (col & 7)));
}

__global__ __launch_bounds__(256, 3) void attn_kernel(
    const f16* __restrict__ Q, const f16* __restrict__ Kg,
    const f16* __restrict__ Vg, f16* __restrict__ O)
{
    __shared__ alignas(16) f16 Kt[64 * 128];
    __shared__ alignas(16) f16 Vt[128 * 64];
    __shared__ alignas(16) f16 Pl[128 * 64];

    const int tid  = threadIdx.x;
    const int wave = tid >> 6, lane = tid & 63;
    const int l16  = lane & 15, quad = lane >> 4;

    const int L  = (int)blockIdx.x;
    const int bh = (L & 7) + 8 * (L >> 7);
    const int qi = 15 - ((L >> 3) & 15);
    const int b  = bh >> 4, h = bh & 15;
    const long base = (long)b * Sc * Dc + (long)h * HDc;
    const float cexp = 0.12751742366f;  // log2(e)/sqrt(128)

    long koff[4];
    f16* kdst[4];
#pragma unroll
    for (int j = 0; j < 4; j++) {
        int row_l = j * 16 + wave * 4 + (lane >> 4);
        int chg   = (lane & 15) ^ ((row_l >> 1) & 7);
        koff[j]   = base + (long)row_l * Dc + chg * 8;
        kdst[j]   = (f16*)&Kt[(j * 16 + wave * 4) * 128];
    }
    const int vd0 = lane * 2;

    f16x8 ones;
#pragma unroll
    for (int i = 0; i < 8; i++) ones[i] = (f16)1.0f;

    unsigned int vreg[2][8];
    auto load_v = [&](int k0) {
#pragma unroll
        for (int j = 0; j < 2; j++) {
            int kk0 = wave * 8 + j * 32;
#pragma unroll
            for (int i2 = 0; i2 < 8; i2++)
                vreg[j][i2] = *(const unsigned int*)&Vg[base + (long)(k0 + kk0 + i2) * Dc + vd0];
        }
    };
    auto load_k_async = [&](int k0) {
#pragma unroll
        for (int j = 0; j < 4; j++)
            async_cp16(Kg + koff[j] + (long)k0 * Dc, kdst[j]);
    };

    const int q0  = qi * 128;
    const int nkt = 2 * qi + 2;
    const int rlo = q0 + wave * 32;

    f16x8 qf[2][4];
#pragma unroll
    for (int im = 0; im < 2; im++)
#pragma unroll
        for (int kk = 0; kk < 4; kk++)
            qf[im][kk] = *(const f16x8*)&Q[base + (long)(q0 + wave * 32 + im * 16 + l16) * Dc
                                           + kk * 32 + quad * 8];

    f32x4 oacc[2][8];
    f32x4 lacc[2];
#pragma unroll
    for (int im = 0; im < 2; im++) {
        lacc[im] = (f32x4){0.f, 0.f, 0.f, 0.f};
#pragma unroll
        for (int nt = 0; nt < 8; nt++) oacc[im][nt] = (f32x4){0.f, 0.f, 0.f, 0.f};
    }

    load_k_async(0);
    load_v(0);
    for (int kt = 0; kt < nkt; kt++) {
        const int k0 = kt * 64;
        __syncthreads();   // A: vmcnt drained -> K[kt] in Kt, vreg = V[kt]; prev LDS reads done
        // ---- write V tile (register transpose) ----
#pragma unroll
        for (int j = 0; j < 2; j++) {
            int kk0 = wave * 8 + j * 32;
            f16x8 lo, hi;
#pragma unroll
            for (int i2 = 0; i2 < 8; i2++) {
                lo[i2] = ((const f16*)&vreg[j][i2])[0];
                hi[i2] = ((const f16*)&vreg[j][i2])[1];
            }
            *(f16x8*)&Vt[swz(vd0,     kk0, 6)] = lo;
            *(f16x8*)&Vt[swz(vd0 + 1, kk0, 6)] = hi;
        }
        __syncthreads();   // B: Vt visible

        const bool compute = (k0 <= rlo + 31);   // wave-uniform causal skip
        f32x4 sf[2][4];
        if (compute) {
            // ---- S = Q K^T ----
#pragma unroll
            for (int im = 0; im < 2; im++)
#pragma unroll
                for (int in = 0; in < 4; in++) sf[im][in] = (f32x4){0.f, 0.f, 0.f, 0.f};
#pragma unroll
            for (int kk = 0; kk < 4; kk++) {
                f16x8 bf[4];
#pragma unroll
                for (int in = 0; in < 4; in++)
                    bf[in] = *(const f16x8*)&Kt[swz(in * 16 + l16, kk * 32 + quad * 8, 7)];
#pragma unroll
                for (int im = 0; im < 2; im++)
#pragma unroll
                    for (int in = 0; in < 4; in++)
                        sf[im][in] = __builtin_amdgcn_mfma_f32_16x16x32_f16(qf[im][kk], bf[in], sf[im][in], 0, 0, 0);
            }
        }
        __syncthreads();   // C: all waves' Kt reads retired -> safe to overwrite Kt

        // ---- prefetch next tile (hidden under softmax+PV, waited at next A) ----
        if (kt + 1 < nkt) {
            load_k_async(k0 + 64);
            load_v(k0 + 64);
        }

        if (compute) {
            // ---- softmax (no max subtraction; scores bounded) ----
#pragma unroll
            for (int im = 0; im < 2; im++) {
                const int rbase = rlo + im * 16;
                const bool need_mask = (k0 + 63 > rbase);
#pragma unroll
                for (int in = 0; in < 4; in++) {
#pragma unroll
                    for (int r = 0; r < 4; r++) {
                        float p = __builtin_amdgcn_exp2f(sf[im][in][r] * cexp);
                        if (need_mask) {
                            int kc  = k0 + in * 16 + l16;
                            int row = rbase + quad * 4 + r;
                            p = (kc <= row) ? p : 0.f;
                        }
                        Pl[swz(wave * 32 + im * 16 + quad * 4 + r, in * 16 + l16, 6)] = (f16)p;
                    }
                }
            }

            // ---- O += P V ; l += P 1  (Pl rows wave-local: no barrier needed) ----
#pragma unroll
            for (int kk = 0; kk < 2; kk++) {
                f16x8 pf[2];
#pragma unroll
                for (int im = 0; im < 2; im++)
                    pf[im] = *(const f16x8*)&Pl[swz(wave * 32 + im * 16 + l16, kk * 32 + quad * 8, 6)];
#pragma unroll
                for (int im = 0; im < 2; im++)
                    lacc[im] = __builtin_amdgcn_mfma_f32_16x16x32_f16(pf[im], ones, lacc[im], 0, 0, 0);
#pragma unroll
                for (int nt = 0; nt < 8; nt++) {
                    f16x8 vf = *(const f16x8*)&Vt[swz(nt * 16 + l16, kk * 32 + quad * 8, 6)];
#pragma unroll
                    for (int im = 0; im < 2; im++)
                        oacc[im][nt] = __builtin_amdgcn_mfma_f32_16x16x32_f16(pf[im], vf, oacc[im][nt], 0, 0, 0);
                }
            }
        }
    }

    // ---- epilogue: O /= l ----
#pragma unroll
    for (int im = 0; im < 2; im++) {
        int qrow = q0 + wave * 32 + im * 16 + quad * 4;
#pragma unroll
        for (int r = 0; r < 4; r++) {
            float inv = 1.0f / lacc[im][r];
#pragma unroll
            for (int nt = 0; nt < 8; nt++)
                O[base + (long)(qrow + r) * Dc + nt * 16 + l16] = (f16)(oacc[im][nt][r] * inv);
        }
    }
}

// ---------------- launch ----------------
extern "C" void kernel_launch(void* const* d_in, const int* in_sizes, int n_in,
                              void* d_out, int out_size, void* d_ws, size_t ws_size,
                              hipStream_t stream)
{
    const float* x  = (const float*)d_in[0];
    const float* wq = (const float*)d_in[1];
    const float* wk = (const float*)d_in[2];
    const float* wv = (const float*)d_in[3];
    const float* wo = (const float*)d_in[4];
    const int*  pos = (const int*)d_in[5];
    float* out = (float*)d_out;

    const long E = (long)Bc * Sc * Dc;
    const long W = (long)Dc * Dc;
    f16* ws  = (f16*)d_ws;
    f16* xh  = ws;
    f16* wqh = ws + E;
    f16* wkh = wqh + W;
    f16* wvh = wkh + W;
    f16* woh = wvh + W;
    f16* Qh  = woh + W;
    f16* Kh  = Qh + E;
    f16* Vh  = Kh + E;
    f16* Oh  = xh;  // alias: xh dead after QKV projections

    cast_all_kernel<<<dim3(16384), 256, 0, stream>>>(x, wq, wk, wv, wo,
                                                     xh, wqh, wkh, wvh, woh);

    dim3 gg((Bc * Sc / 256) * (Dc / 256));   // 32*8 = 256 blocks, 512 threads
    gemm_bt8<f16><<<gg, 512, 0, stream>>>(xh, wqh, Qh, Bc * Sc, Dc, Dc);
    gemm_bt8<f16><<<gg, 512, 0, stream>>>(xh, wkh, Kh, Bc * Sc, Dc, Dc);
    gemm_bt8<f16><<<gg, 512, 0, stream>>>(xh, wvh, Vh, Bc * Sc, Dc, Dc);

    long npairs = (long)Bc * Sc * Hc * (HDc / 2);
    rope_kernel<<<dim3(2 * npairs / 256), 256, 0, stream>>>(Qh, Kh, pos, npairs);

    attn_kernel<<<dim3(1024), 256, 0, stream>>>(Qh, Kh, Vh, Oh);

    gemm_bt8<float><<<gg, 512, 0, stream>>>(Oh, woh, out, Bc * Sc, Dc, Dc);
}

// Round 3
// 631.239 us; speedup vs baseline: 1.6377x; 1.6377x over previous
//
#include <hip/hip_runtime.h>
#include <cstdint>

typedef _Float16 f16;
typedef __attribute__((ext_vector_type(8))) _Float16 f16x8;
typedef __attribute__((ext_vector_type(4))) float f32x4;

constexpr int Bc  = 4;
constexpr int Sc  = 2048;
constexpr int Dc  = 2048;
constexpr int Hc  = 16;
constexpr int HDc = 128;

// ---------------- fused fp32 -> fp16 cast (all 5 tensors, 1 launch) ----------------
__global__ void cast_all_kernel(const float* __restrict__ x,  const float* __restrict__ wq,
                                const float* __restrict__ wk, const float* __restrict__ wv,
                                const float* __restrict__ wo,
                                f16* __restrict__ xh,  f16* __restrict__ wqh,
                                f16* __restrict__ wkh, f16* __restrict__ wvh,
                                f16* __restrict__ woh)
{
    long bid = blockIdx.x;
    const float* src; f16* dst; long off;
    if (bid < 8192)       { src = x;  dst = xh;  off = bid * 2048; }
    else {
        int r = (int)((bid - 8192) >> 11);
        off = ((bid - 8192) & 2047) * 2048;
        switch (r) {
            case 0:  src = wq; dst = wqh; break;
            case 1:  src = wk; dst = wkh; break;
            case 2:  src = wv; dst = wvh; break;
            default: src = wo; dst = woh; break;
        }
    }
    long i = off + (long)threadIdx.x * 8;
    float4 a = *(const float4*)(src + i);
    float4 b = *(const float4*)(src + i + 4);
    f16x8 o = { (f16)a.x, (f16)a.y, (f16)a.z, (f16)a.w,
                (f16)b.x, (f16)b.y, (f16)b.z, (f16)b.w };
    *(f16x8*)(dst + i) = o;
}

// ---------------- async global->LDS 16B/lane ----------------
__device__ __forceinline__ void async_cp16(const f16* g, f16* l)
{
    __builtin_amdgcn_global_load_lds(
        (__attribute__((address_space(1))) void*)(g),
        (__attribute__((address_space(3))) void*)(l), 16, 0, 0);
}

// ---------------- GEMM: C[m,n] = sum_k A[m,k] * W[n,k] ----------------
// 256x256 tile, 512 threads (8 waves, 2M x 4N), BK=32, ring of 4 LDS K-slots.
// Intra-tile lockstep barriers removed (ring-4: slot kt&3 re-staged 2 iters /
// >=2 tile-end barriers after last read; skew bounded <1 iter by tile-end
// barrier). Counted vmcnt(4) at tile end (t+1 landed, t+2 in flight).
// R1->R2 A/B: barrier removal neutral (457 vs 460 us for 4 GEMMs) - kept.
template<typename OUT_T>
__global__ __launch_bounds__(512, 2) void gemm_bt8(
    const f16* __restrict__ A, const f16* __restrict__ W,
    OUT_T* __restrict__ C, int M, int N, int K)
{
    __shared__ alignas(16) f16 As[4][8192];   // [slot][256 rows x 32 cols]
    __shared__ alignas(16) f16 Bs[4][8192];

    const int tid  = threadIdx.x;
    const int wave = tid >> 6, lane = tid & 63;
    const int l16  = lane & 15, quad = lane >> 4;
    const int wm   = wave >> 2, wn = wave & 3;

    // XCD-bijective block swizzle (nwg is a multiple of 8 here: 32x8=256)
    const int nwg = (int)gridDim.x;
    int bid = (int)blockIdx.x;
    int wg  = ((nwg & 7) == 0) ? ((bid & 7) * (nwg >> 3) + (bid >> 3)) : bid;
    const int ntile = N >> 8;
    const int mt = wg / ntile, nt = wg % ntile;
    const int m0 = mt << 8, n0 = nt << 8;

    // ---- staging addresses (thread t covers phys row=t>>2, chunk=t&3) ----
    const int  prow = tid >> 2;                               // 0..127
    const int  lch  = (((tid & 3) ^ ((prow >> 1) & 3)) << 3); // logical f16 col
    const f16* Asrc = A + (long)(m0 + prow) * K + lch;
    const f16* Bsrc = W + (long)(n0 + prow) * K + lch;
    const long rsk  = (long)K << 7;           // +128 rows
    const int  dst0 = wave << 9;              // wave-uniform LDS base (f16)

    const int nkt = K >> 5;

    auto stA = [&](int kt) {
        const f16* g = Asrc + ((long)kt << 5);
        int s = kt & 3;
        async_cp16(g,       &As[s][dst0]);
        async_cp16(g + rsk, &As[s][4096 + dst0]);
    };
    auto stB = [&](int kt) {
        const f16* g = Bsrc + ((long)kt << 5);
        int s = kt & 3;
        async_cp16(g,       &Bs[s][dst0]);
        async_cp16(g + rsk, &Bs[s][4096 + dst0]);
    };

    // ---- fragment read addressing (swizzled chunk is lane-constant) ----
    const int coff = ((quad ^ ((l16 >> 1) & 3)) << 3);
    const int arow = wm * 128 + l16;          // + i*16
    const int brow = wn * 64  + l16;          // + j*16

    f32x4 acc[8][4];
#pragma unroll
    for (int i = 0; i < 8; i++)
#pragma unroll
        for (int j = 0; j < 4; j++) acc[i][j] = (f32x4){0.f, 0.f, 0.f, 0.f};

    // ---- prologue: stage tiles 0 and 1 ----
    stA(0); stB(0);
    if (nkt > 1) {
        stA(1); stB(1);
        asm volatile("s_waitcnt vmcnt(4)" ::: "memory");
    } else {
        asm volatile("s_waitcnt vmcnt(0)" ::: "memory");
    }
    __builtin_amdgcn_s_barrier();
    __builtin_amdgcn_sched_barrier(0);

    for (int kt = 0; kt < nkt; ++kt) {
        const int s = kt & 3;
        const f16* as = &As[s][(long)arow * 32 + coff];
        const f16* bs = &Bs[s][(long)brow * 32 + coff];

        // ---- phase 1: B all + A low-half, stage A(t+2), MFMA quadrant 0 ----
        f16x8 bfr[4], afr[4];
#pragma unroll
        for (int j = 0; j < 4; ++j) bfr[j] = *(const f16x8*)(bs + j * 512);
#pragma unroll
        for (int i = 0; i < 4; ++i) afr[i] = *(const f16x8*)(as + i * 512);
        if (kt + 2 < nkt) stA(kt + 2);
        asm volatile("s_waitcnt lgkmcnt(0)" ::: "memory");
        __builtin_amdgcn_sched_barrier(0);
        __builtin_amdgcn_s_setprio(1);
#pragma unroll
        for (int i = 0; i < 4; ++i)
#pragma unroll
            for (int j = 0; j < 4; ++j)
                acc[i][j] = __builtin_amdgcn_mfma_f32_16x16x32_f16(afr[i], bfr[j], acc[i][j], 0, 0, 0);
        __builtin_amdgcn_s_setprio(0);

        // ---- phase 2: A high-half, stage B(t+2), MFMA quadrant 1 ----
        f16x8 afr2[4];
#pragma unroll
        for (int i = 0; i < 4; ++i) afr2[i] = *(const f16x8*)(as + (i + 4) * 512);
        if (kt + 2 < nkt) stB(kt + 2);
        asm volatile("s_waitcnt lgkmcnt(0)" ::: "memory");
        __builtin_amdgcn_sched_barrier(0);
        __builtin_amdgcn_s_setprio(1);
#pragma unroll
        for (int i = 0; i < 4; ++i)
#pragma unroll
            for (int j = 0; j < 4; ++j)
                acc[i + 4][j] = __builtin_amdgcn_mfma_f32_16x16x32_f16(afr2[i], bfr[j], acc[i + 4][j], 0, 0, 0);
        __builtin_amdgcn_s_setprio(0);

        // ---- tile boundary: counted wait (tile t+1 landed, t+2 in flight) ----
        if (kt + 2 < nkt) asm volatile("s_waitcnt vmcnt(4)" ::: "memory");
        else              asm volatile("s_waitcnt vmcnt(0)" ::: "memory");
        __builtin_amdgcn_s_barrier();
        __builtin_amdgcn_sched_barrier(0);
    }

    // ---- epilogue ----
#pragma unroll
    for (int i = 0; i < 8; ++i) {
        int row = m0 + wm * 128 + i * 16 + quad * 4;
#pragma unroll
        for (int j = 0; j < 4; ++j) {
            int col = n0 + wn * 64 + j * 16 + l16;
#pragma unroll
            for (int r = 0; r < 4; ++r)
                C[(long)(row + r) * N + col] = (OUT_T)acc[i][j][r];
        }
    }
}

// ---------------- RoPE (in-place on fp16 Q and K) ----------------
__global__ void rope_kernel(f16* __restrict__ Q, f16* __restrict__ K,
                            const int* __restrict__ pos, long npairs)
{
    long t = (long)blockIdx.x * blockDim.x + threadIdx.x;
    if (t >= 2 * npairs) return;
    f16* P = Q;
    long p = t;
    if (p >= npairs) { P = K; p -= npairs; }
    int  i    = (int)(p & 63);
    long rest = p >> 6;
    int  h    = (int)(rest & (Hc - 1));
    long row  = rest >> 4;
    int  s    = (int)(row & (Sc - 1));

    float inv = expf(-(float)i * (9.210340371976184f / 64.0f));
    float ang = (float)pos[s] * inv;
    float sn, cs;
    sincosf(ang, &sn, &cs);

    long idx = row * Dc + (long)h * HDc + 2 * i;
    unsigned int u = *(const unsigned int*)(P + idx);
    float x1 = (float)((const f16*)&u)[0];
    float x2 = (float)((const f16*)&u)[1];
    f16 o[2] = { (f16)(x1 * cs - x2 * sn), (f16)(x1 * sn + x2 * cs) };
    *(unsigned int*)(P + idx) = *(const unsigned int*)o;
}

// ---------------- Flash attention v6 (causal) ----------------
// R3: single-buffered Kt (48K LDS -> 3 blocks/CU LDS-wise) BUT back to
// __launch_bounds__(256,2). R2's (256,3) clamped VGPR to 84 -> mass spill
// (FETCH 49->733MB, WRITE 33->447MB, 180->577us). With bound=2 the compiler
// gets 256 regs; sf liveness shortened by moving softmax BEFORE barrier C
// (softmax doesn't read Kt) so live-across-barrier set is ~oacc+qf+lacc
// (~130-150 regs) -> if <=170, HW gives 3 blocks/CU.
// Per-tile: A(drain: Kt=K[kt], vreg=V[kt]) -> write Vt -> B -> QK^T ->
// softmax->Pl -> C(Kt reads retired) -> issue K-DMA[kt+1]+load_v[kt+1]
// (hidden under PV, waited at next A) -> PV.
__device__ __forceinline__ int swz(int row, int col, int ldshift) {
    return (row << ldshift) + (((((col >> 3) ^ ((row >> 1) & 7)) << 3) | (col & 7)));
}

__global__ __launch_bounds__(256, 2) void attn_kernel(
    const f16* __restrict__ Q, const f16* __restrict__ Kg,
    const f16* __restrict__ Vg, f16* __restrict__ O)
{
    __shared__ alignas(16) f16 Kt[64 * 128];
    __shared__ alignas(16) f16 Vt[128 * 64];
    __shared__ alignas(16) f16 Pl[128 * 64];

    const int tid  = threadIdx.x;
    const int wave = tid >> 6, lane = tid & 63;
    const int l16  = lane & 15, quad = lane >> 4;

    const int L  = (int)blockIdx.x;
    const int bh = (L & 7) + 8 * (L >> 7);
    const int qi = 15 - ((L >> 3) & 15);
    const int b  = bh >> 4, h = bh & 15;
    const long base = (long)b * Sc * Dc + (long)h * HDc;
    const float cexp = 0.12751742366f;  // log2(e)/sqrt(128)

    long koff[4];
    f16* kdst[4];
#pragma unroll
    for (int j = 0; j < 4; j++) {
        int row_l = j * 16 + wave * 4 + (lane >> 4);
        int chg   = (lane & 15) ^ ((row_l >> 1) & 7);
        koff[j]   = base + (long)row_l * Dc + chg * 8;
        kdst[j]   = (f16*)&Kt[(j * 16 + wave * 4) * 128];
    }
    const int vd0 = lane * 2;

    f16x8 ones;
#pragma unroll
    for (int i = 0; i < 8; i++) ones[i] = (f16)1.0f;

    unsigned int vreg[2][8];
    auto load_v = [&](int k0) {
#pragma unroll
        for (int j = 0; j < 2; j++) {
            int kk0 = wave * 8 + j * 32;
#pragma unroll
            for (int i2 = 0; i2 < 8; i2++)
                vreg[j][i2] = *(const unsigned int*)&Vg[base + (long)(k0 + kk0 + i2) * Dc + vd0];
        }
    };
    auto load_k_async = [&](int k0) {
#pragma unroll
        for (int j = 0; j < 4; j++)
            async_cp16(Kg + koff[j] + (long)k0 * Dc, kdst[j]);
    };

    const int q0  = qi * 128;
    const int nkt = 2 * qi + 2;
    const int rlo = q0 + wave * 32;

    f16x8 qf[2][4];
#pragma unroll
    for (int im = 0; im < 2; im++)
#pragma unroll
        for (int kk = 0; kk < 4; kk++)
            qf[im][kk] = *(const f16x8*)&Q[base + (long)(q0 + wave * 32 + im * 16 + l16) * Dc
                                           + kk * 32 + quad * 8];

    f32x4 oacc[2][8];
    f32x4 lacc[2];
#pragma unroll
    for (int im = 0; im < 2; im++) {
        lacc[im] = (f32x4){0.f, 0.f, 0.f, 0.f};
#pragma unroll
        for (int nt = 0; nt < 8; nt++) oacc[im][nt] = (f32x4){0.f, 0.f, 0.f, 0.f};
    }

    load_k_async(0);
    load_v(0);
    for (int kt = 0; kt < nkt; kt++) {
        const int k0 = kt * 64;
        __syncthreads();   // A: vmcnt drained -> K[kt] in Kt, vreg = V[kt]; prev LDS reads done
        // ---- write V tile (register transpose) ----
#pragma unroll
        for (int j = 0; j < 2; j++) {
            int kk0 = wave * 8 + j * 32;
            f16x8 lo, hi;
#pragma unroll
            for (int i2 = 0; i2 < 8; i2++) {
                lo[i2] = ((const f16*)&vreg[j][i2])[0];
                hi[i2] = ((const f16*)&vreg[j][i2])[1];
            }
            *(f16x8*)&Vt[swz(vd0,     kk0, 6)] = lo;
            *(f16x8*)&Vt[swz(vd0 + 1, kk0, 6)] = hi;
        }
        __syncthreads();   // B: Vt visible

        const bool compute = (k0 <= rlo + 31);   // wave-uniform causal skip
        if (compute) {
            // ---- S = Q K^T ----
            f32x4 sf[2][4];
#pragma unroll
            for (int im = 0; im < 2; im++)
#pragma unroll
                for (int in = 0; in < 4; in++) sf[im][in] = (f32x4){0.f, 0.f, 0.f, 0.f};
#pragma unroll
            for (int kk = 0; kk < 4; kk++) {
                f16x8 bf[4];
#pragma unroll
                for (int in = 0; in < 4; in++)
                    bf[in] = *(const f16x8*)&Kt[swz(in * 16 + l16, kk * 32 + quad * 8, 7)];
#pragma unroll
                for (int im = 0; im < 2; im++)
#pragma unroll
                    for (int in = 0; in < 4; in++)
                        sf[im][in] = __builtin_amdgcn_mfma_f32_16x16x32_f16(qf[im][kk], bf[in], sf[im][in], 0, 0, 0);
            }

            // ---- softmax -> Pl (consumes sf BEFORE barrier C: short liveness) ----
#pragma unroll
            for (int im = 0; im < 2; im++) {
                const int rbase = rlo + im * 16;
                const bool need_mask = (k0 + 63 > rbase);
#pragma unroll
                for (int in = 0; in < 4; in++) {
#pragma unroll
                    for (int r = 0; r < 4; r++) {
                        float p = __builtin_amdgcn_exp2f(sf[im][in][r] * cexp);
                        if (need_mask) {
                            int kc  = k0 + in * 16 + l16;
                            int row = rbase + quad * 4 + r;
                            p = (kc <= row) ? p : 0.f;
                        }
                        Pl[swz(wave * 32 + im * 16 + quad * 4 + r, in * 16 + l16, 6)] = (f16)p;
                    }
                }
            }
        }
        __syncthreads();   // C: all waves' Kt reads retired -> safe to overwrite Kt

        // ---- prefetch next tile (hidden under PV, waited at next A) ----
        if (kt + 1 < nkt) {
            load_k_async(k0 + 64);
            load_v(k0 + 64);
        }

        if (compute) {
            // ---- O += P V ; l += P 1  (Pl rows wave-local) ----
#pragma unroll
            for (int kk = 0; kk < 2; kk++) {
                f16x8 pf[2];
#pragma unroll
                for (int im = 0; im < 2; im++)
                    pf[im] = *(const f16x8*)&Pl[swz(wave * 32 + im * 16 + l16, kk * 32 + quad * 8, 6)];
#pragma unroll
                for (int im = 0; im < 2; im++)
                    lacc[im] = __builtin_amdgcn_mfma_f32_16x16x32_f16(pf[im], ones, lacc[im], 0, 0, 0);
#pragma unroll
                for (int nt = 0; nt < 8; nt++) {
                    f16x8 vf = *(const f16x8*)&Vt[swz(nt * 16 + l16, kk * 32 + quad * 8, 6)];
#pragma unroll
                    for (int im = 0; im < 2; im++)
                        oacc[im][nt] = __builtin_amdgcn_mfma_f32_16x16x32_f16(pf[im], vf, oacc[im][nt], 0, 0, 0);
                }
            }
        }
    }

    // ---- epilogue: O /= l ----
#pragma unroll
    for (int im = 0; im < 2; im++) {
        int qrow = q0 + wave * 32 + im * 16 + quad * 4;
#pragma unroll
        for (int r = 0; r < 4; r++) {
            float inv = 1.0f / lacc[im][r];
#pragma unroll
            for (int nt = 0; nt < 8; nt++)
                O[base + (long)(qrow + r) * Dc + nt * 16 + l16] = (f16)(oacc[im][nt][r] * inv);
        }
    }
}

// ---------------- launch ----------------
extern "C" void kernel_launch(void* const* d_in, const int* in_sizes, int n_in,
                              void* d_out, int out_size, void* d_ws, size_t ws_size,
                              hipStream_t stream)
{
    const float* x  = (const float*)d_in[0];
    const float* wq = (const float*)d_in[1];
    const float* wk = (const float*)d_in[2];
    const float* wv = (const float*)d_in[3];
    const float* wo = (const float*)d_in[4];
    const int*  pos = (const int*)d_in[5];
    float* out = (float*)d_out;

    const long E = (long)Bc * Sc * Dc;
    const long W = (long)Dc * Dc;
    f16* ws  = (f16*)d_ws;
    f16* xh  = ws;
    f16* wqh = ws + E;
    f16* wkh = wqh + W;
    f16* wvh = wkh + W;
    f16* woh = wvh + W;
    f16* Qh  = woh + W;
    f16* Kh  = Qh + E;
    f16* Vh  = Kh + E;
    f16* Oh  = xh;  // alias: xh dead after QKV projections

    cast_all_kernel<<<dim3(16384), 256, 0, stream>>>(x, wq, wk, wv, wo,
                                                     xh, wqh, wkh, wvh, woh);

    dim3 gg((Bc * Sc / 256) * (Dc / 256));   // 32*8 = 256 blocks, 512 threads
    gemm_bt8<f16><<<gg, 512, 0, stream>>>(xh, wqh, Qh, Bc * Sc, Dc, Dc);
    gemm_bt8<f16><<<gg, 512, 0, stream>>>(xh, wkh, Kh, Bc * Sc, Dc, Dc);
    gemm_bt8<f16><<<gg, 512, 0, stream>>>(xh, wvh, Vh, Bc * Sc, Dc, Dc);

    long npairs = (long)Bc * Sc * Hc * (HDc / 2);
    rope_kernel<<<dim3(2 * npairs / 256), 256, 0, stream>>>(Qh, Kh, pos, npairs);

    attn_kernel<<<dim3(1024), 256, 0, stream>>>(Qh, Kh, Vh, Oh);

    gemm_bt8<float><<<gg, 512, 0, stream>>>(Oh, woh, out, Bc * Sc, Dc, Dc);
}

// Round 4
// 618.186 us; speedup vs baseline: 1.6723x; 1.0211x over previous
//
#include <hip/hip_runtime.h>
#include <cstdint>

typedef _Float16 f16;
typedef __attribute__((ext_vector_type(8))) _Float16 f16x8;
typedef __attribute__((ext_vector_type(4))) float f32x4;

constexpr int Bc  = 4;
constexpr int Sc  = 2048;
constexpr int Dc  = 2048;
constexpr int Hc  = 16;
constexpr int HDc = 128;
constexpr int LDq = 3 * Dc;   // fused QKV row stride (6144)

// ---------------- fused fp32 -> fp16 cast (all 5 tensors, 1 launch) ----------------
__global__ void cast_all_kernel(const float* __restrict__ x,  const float* __restrict__ wq,
                                const float* __restrict__ wk, const float* __restrict__ wv,
                                const float* __restrict__ wo,
                                f16* __restrict__ xh,  f16* __restrict__ wqh,
                                f16* __restrict__ wkh, f16* __restrict__ wvh,
                                f16* __restrict__ woh)
{
    long bid = blockIdx.x;
    const float* src; f16* dst; long off;
    if (bid < 8192)       { src = x;  dst = xh;  off = bid * 2048; }
    else {
        int r = (int)((bid - 8192) >> 11);
        off = ((bid - 8192) & 2047) * 2048;
        switch (r) {
            case 0:  src = wq; dst = wqh; break;
            case 1:  src = wk; dst = wkh; break;
            case 2:  src = wv; dst = wvh; break;
            default: src = wo; dst = woh; break;
        }
    }
    long i = off + (long)threadIdx.x * 8;
    float4 a = *(const float4*)(src + i);
    float4 b = *(const float4*)(src + i + 4);
    f16x8 o = { (f16)a.x, (f16)a.y, (f16)a.z, (f16)a.w,
                (f16)b.x, (f16)b.y, (f16)b.z, (f16)b.w };
    *(f16x8*)(dst + i) = o;
}

// ---------------- RoPE cos/sin table (S x 64 pairs, 1 MB) ----------------
__global__ void gen_rope_tab(const int* __restrict__ pos, float2* __restrict__ tab)
{
    int s = blockIdx.x, i = threadIdx.x;
    float inv = expf(-(float)i * (9.210340371976184f / 64.0f));
    float ang = (float)pos[s] * inv;
    float sn, cs;
    sincosf(ang, &sn, &cs);
    tab[s * 64 + i] = make_float2(cs, sn);
}

// ---------------- async global->LDS 16B/lane ----------------
__device__ __forceinline__ void async_cp16(const f16* g, f16* l)
{
    __builtin_amdgcn_global_load_lds(
        (__attribute__((address_space(1))) void*)(g),
        (__attribute__((address_space(3))) void*)(l), 16, 0, 0);
}

// ---------------- GEMM: C[m,n] = sum_k A[m,k] * W[n,k] ----------------
// 256x256 tile, 512 threads (8 waves, 2M x 4N), BK=32, ring of 4 LDS K-slots,
// counted vmcnt(4) at tile end (t+1 landed, t+2 in flight), no intra-tile
// lockstep barriers (R1->R2 A/B: neutral).
// ROPE=true: epilogue applies rotary embedding to cols < 4096 (Q and K slices
// of the fused QKV output) on the f32 accumulator: pair partner via
// __shfl_xor(v,1) (cols 2i/2i+1 sit in adjacent lanes), cos/sin from tab.
// Branch is wave-uniform (region boundary 4096 is a multiple of the tile).
template<typename OUT_T, bool ROPE>
__global__ __launch_bounds__(512, 2) void gemm_bt8(
    const f16* __restrict__ A, const f16* __restrict__ W,
    OUT_T* __restrict__ C, const float2* __restrict__ tab,
    int M, int N, int K)
{
    __shared__ alignas(16) f16 As[4][8192];   // [slot][256 rows x 32 cols]
    __shared__ alignas(16) f16 Bs[4][8192];

    const int tid  = threadIdx.x;
    const int wave = tid >> 6, lane = tid & 63;
    const int l16  = lane & 15, quad = lane >> 4;
    const int wm   = wave >> 2, wn = wave & 3;

    // XCD-bijective block swizzle (nwg % 8 == 0 for all our grids)
    const int nwg = (int)gridDim.x;
    int bid = (int)blockIdx.x;
    int wg  = ((nwg & 7) == 0) ? ((bid & 7) * (nwg >> 3) + (bid >> 3)) : bid;
    const int ntile = N >> 8;
    const int mt = wg / ntile, nt = wg % ntile;
    const int m0 = mt << 8, n0 = nt << 8;

    // ---- staging addresses (thread t covers phys row=t>>2, chunk=t&3) ----
    const int  prow = tid >> 2;                               // 0..127
    const int  lch  = (((tid & 3) ^ ((prow >> 1) & 3)) << 3); // logical f16 col
    const f16* Asrc = A + (long)(m0 + prow) * K + lch;
    const f16* Bsrc = W + (long)(n0 + prow) * K + lch;
    const long rsk  = (long)K << 7;           // +128 rows
    const int  dst0 = wave << 9;              // wave-uniform LDS base (f16)

    const int nkt = K >> 5;

    auto stA = [&](int kt) {
        const f16* g = Asrc + ((long)kt << 5);
        int s = kt & 3;
        async_cp16(g,       &As[s][dst0]);
        async_cp16(g + rsk, &As[s][4096 + dst0]);
    };
    auto stB = [&](int kt) {
        const f16* g = Bsrc + ((long)kt << 5);
        int s = kt & 3;
        async_cp16(g,       &Bs[s][dst0]);
        async_cp16(g + rsk, &Bs[s][4096 + dst0]);
    };

    // ---- fragment read addressing (swizzled chunk is lane-constant) ----
    const int coff = ((quad ^ ((l16 >> 1) & 3)) << 3);
    const int arow = wm * 128 + l16;          // + i*16
    const int brow = wn * 64  + l16;          // + j*16

    f32x4 acc[8][4];
#pragma unroll
    for (int i = 0; i < 8; i++)
#pragma unroll
        for (int j = 0; j < 4; j++) acc[i][j] = (f32x4){0.f, 0.f, 0.f, 0.f};

    // ---- prologue: stage tiles 0 and 1 ----
    stA(0); stB(0);
    if (nkt > 1) {
        stA(1); stB(1);
        asm volatile("s_waitcnt vmcnt(4)" ::: "memory");
    } else {
        asm volatile("s_waitcnt vmcnt(0)" ::: "memory");
    }
    __builtin_amdgcn_s_barrier();
    __builtin_amdgcn_sched_barrier(0);

    for (int kt = 0; kt < nkt; ++kt) {
        const int s = kt & 3;
        const f16* as = &As[s][(long)arow * 32 + coff];
        const f16* bs = &Bs[s][(long)brow * 32 + coff];

        // ---- phase 1: B all + A low-half, stage A(t+2), MFMA quadrant 0 ----
        f16x8 bfr[4], afr[4];
#pragma unroll
        for (int j = 0; j < 4; ++j) bfr[j] = *(const f16x8*)(bs + j * 512);
#pragma unroll
        for (int i = 0; i < 4; ++i) afr[i] = *(const f16x8*)(as + i * 512);
        if (kt + 2 < nkt) stA(kt + 2);
        asm volatile("s_waitcnt lgkmcnt(0)" ::: "memory");
        __builtin_amdgcn_sched_barrier(0);
        __builtin_amdgcn_s_setprio(1);
#pragma unroll
        for (int i = 0; i < 4; ++i)
#pragma unroll
            for (int j = 0; j < 4; ++j)
                acc[i][j] = __builtin_amdgcn_mfma_f32_16x16x32_f16(afr[i], bfr[j], acc[i][j], 0, 0, 0);
        __builtin_amdgcn_s_setprio(0);

        // ---- phase 2: A high-half, stage B(t+2), MFMA quadrant 1 ----
        f16x8 afr2[4];
#pragma unroll
        for (int i = 0; i < 4; ++i) afr2[i] = *(const f16x8*)(as + (i + 4) * 512);
        if (kt + 2 < nkt) stB(kt + 2);
        asm volatile("s_waitcnt lgkmcnt(0)" ::: "memory");
        __builtin_amdgcn_sched_barrier(0);
        __builtin_amdgcn_s_setprio(1);
#pragma unroll
        for (int i = 0; i < 4; ++i)
#pragma unroll
            for (int j = 0; j < 4; ++j)
                acc[i + 4][j] = __builtin_amdgcn_mfma_f32_16x16x32_f16(afr2[i], bfr[j], acc[i + 4][j], 0, 0, 0);
        __builtin_amdgcn_s_setprio(0);

        // ---- tile boundary: counted wait (tile t+1 landed, t+2 in flight) ----
        if (kt + 2 < nkt) asm volatile("s_waitcnt vmcnt(4)" ::: "memory");
        else              asm volatile("s_waitcnt vmcnt(0)" ::: "memory");
        __builtin_amdgcn_s_barrier();
        __builtin_amdgcn_sched_barrier(0);
    }

    // ---- epilogue (optionally fused RoPE on f32 acc) ----
#pragma unroll
    for (int i = 0; i < 8; ++i) {
        int row = m0 + wm * 128 + i * 16 + quad * 4;
#pragma unroll
        for (int j = 0; j < 4; ++j) {
            int col = n0 + wn * 64 + j * 16 + l16;
            if (ROPE && col < 4096) {           // Q or K slice: apply rotary
                const int  ip = (col & 127) >> 1;
                const bool ev = !(col & 1);
#pragma unroll
                for (int r = 0; r < 4; ++r) {
                    float v = acc[i][j][r];
                    float p = __shfl_xor(v, 1, 64);
                    int   sfx = (row + r) & (Sc - 1);
                    float2 cs = tab[sfx * 64 + ip];
                    float o = ev ? (v * cs.x - p * cs.y) : (p * cs.y + v * cs.x);
                    C[(long)(row + r) * N + col] = (OUT_T)o;
                }
            } else {
#pragma unroll
                for (int r = 0; r < 4; ++r)
                    C[(long)(row + r) * N + col] = (OUT_T)acc[i][j][r];
            }
        }
    }
}

// ---------------- Flash attention v6 (causal), QKV row stride = LDq ----------------
// Q/K/V are column slices of the fused [M][6144] projection output; O is written
// to a dense [M][2048] buffer. Schedule unchanged from R3 (171us, passing):
// A(drain: Kt=K[kt], vreg=V[kt]) -> write Vt -> B -> QK^T -> softmax->Pl ->
// C(Kt reads retired) -> issue K-DMA[kt+1]+load_v[kt+1] (hidden under PV) -> PV.
__device__ __forceinline__ int swz(int row, int col, int ldshift) {
    return (row << ldshift) + (((((col >> 3) ^ ((row >> 1) & 7)) << 3) | (col & 7)));
}

__global__ __launch_bounds__(256, 2) void attn_kernel(
    const f16* __restrict__ Q, const f16* __restrict__ Kg,
    const f16* __restrict__ Vg, f16* __restrict__ O)
{
    __shared__ alignas(16) f16 Kt[64 * 128];
    __shared__ alignas(16) f16 Vt[128 * 64];
    __shared__ alignas(16) f16 Pl[128 * 64];

    const int tid  = threadIdx.x;
    const int wave = tid >> 6, lane = tid & 63;
    const int l16  = lane & 15, quad = lane >> 4;

    const int L  = (int)blockIdx.x;
    const int bh = (L & 7) + 8 * (L >> 7);
    const int qi = 15 - ((L >> 3) & 15);
    const int b  = bh >> 4, h = bh & 15;
    const long bi = (long)b * Sc * LDq + (long)h * HDc;   // QKV input base
    const long bo = (long)b * Sc * Dc  + (long)h * HDc;   // O output base
    const float cexp = 0.12751742366f;  // log2(e)/sqrt(128)

    long koff[4];
    f16* kdst[4];
#pragma unroll
    for (int j = 0; j < 4; j++) {
        int row_l = j * 16 + wave * 4 + (lane >> 4);
        int chg   = (lane & 15) ^ ((row_l >> 1) & 7);
        koff[j]   = bi + (long)row_l * LDq + chg * 8;
        kdst[j]   = (f16*)&Kt[(j * 16 + wave * 4) * 128];
    }
    const int vd0 = lane * 2;

    f16x8 ones;
#pragma unroll
    for (int i = 0; i < 8; i++) ones[i] = (f16)1.0f;

    unsigned int vreg[2][8];
    auto load_v = [&](int k0) {
#pragma unroll
        for (int j = 0; j < 2; j++) {
            int kk0 = wave * 8 + j * 32;
#pragma unroll
            for (int i2 = 0; i2 < 8; i2++)
                vreg[j][i2] = *(const unsigned int*)&Vg[bi + (long)(k0 + kk0 + i2) * LDq + vd0];
        }
    };
    auto load_k_async = [&](int k0) {
#pragma unroll
        for (int j = 0; j < 4; j++)
            async_cp16(Kg + koff[j] + (long)k0 * LDq, kdst[j]);
    };

    const int q0  = qi * 128;
    const int nkt = 2 * qi + 2;
    const int rlo = q0 + wave * 32;

    f16x8 qf[2][4];
#pragma unroll
    for (int im = 0; im < 2; im++)
#pragma unroll
        for (int kk = 0; kk < 4; kk++)
            qf[im][kk] = *(const f16x8*)&Q[bi + (long)(q0 + wave * 32 + im * 16 + l16) * LDq
                                           + kk * 32 + quad * 8];

    f32x4 oacc[2][8];
    f32x4 lacc[2];
#pragma unroll
    for (int im = 0; im < 2; im++) {
        lacc[im] = (f32x4){0.f, 0.f, 0.f, 0.f};
#pragma unroll
        for (int nt = 0; nt < 8; nt++) oacc[im][nt] = (f32x4){0.f, 0.f, 0.f, 0.f};
    }

    load_k_async(0);
    load_v(0);
    for (int kt = 0; kt < nkt; kt++) {
        const int k0 = kt * 64;
        __syncthreads();   // A: vmcnt drained -> K[kt] in Kt, vreg = V[kt]; prev LDS reads done
        // ---- write V tile (register transpose) ----
#pragma unroll
        for (int j = 0; j < 2; j++) {
            int kk0 = wave * 8 + j * 32;
            f16x8 lo, hi;
#pragma unroll
            for (int i2 = 0; i2 < 8; i2++) {
                lo[i2] = ((const f16*)&vreg[j][i2])[0];
                hi[i2] = ((const f16*)&vreg[j][i2])[1];
            }
            *(f16x8*)&Vt[swz(vd0,     kk0, 6)] = lo;
            *(f16x8*)&Vt[swz(vd0 + 1, kk0, 6)] = hi;
        }
        __syncthreads();   // B: Vt visible

        const bool compute = (k0 <= rlo + 31);   // wave-uniform causal skip
        if (compute) {
            // ---- S = Q K^T ----
            f32x4 sf[2][4];
#pragma unroll
            for (int im = 0; im < 2; im++)
#pragma unroll
                for (int in = 0; in < 4; in++) sf[im][in] = (f32x4){0.f, 0.f, 0.f, 0.f};
#pragma unroll
            for (int kk = 0; kk < 4; kk++) {
                f16x8 bf[4];
#pragma unroll
                for (int in = 0; in < 4; in++)
                    bf[in] = *(const f16x8*)&Kt[swz(in * 16 + l16, kk * 32 + quad * 8, 7)];
#pragma unroll
                for (int im = 0; im < 2; im++)
#pragma unroll
                    for (int in = 0; in < 4; in++)
                        sf[im][in] = __builtin_amdgcn_mfma_f32_16x16x32_f16(qf[im][kk], bf[in], sf[im][in], 0, 0, 0);
            }

            // ---- softmax -> Pl (consumes sf BEFORE barrier C: short liveness) ----
#pragma unroll
            for (int im = 0; im < 2; im++) {
                const int rbase = rlo + im * 16;
                const bool need_mask = (k0 + 63 > rbase);
#pragma unroll
                for (int in = 0; in < 4; in++) {
#pragma unroll
                    for (int r = 0; r < 4; r++) {
                        float p = __builtin_amdgcn_exp2f(sf[im][in][r] * cexp);
                        if (need_mask) {
                            int kc  = k0 + in * 16 + l16;
                            int row = rbase + quad * 4 + r;
                            p = (kc <= row) ? p : 0.f;
                        }
                        Pl[swz(wave * 32 + im * 16 + quad * 4 + r, in * 16 + l16, 6)] = (f16)p;
                    }
                }
            }
        }
        __syncthreads();   // C: all waves' Kt reads retired -> safe to overwrite Kt

        // ---- prefetch next tile (hidden under PV, waited at next A) ----
        if (kt + 1 < nkt) {
            load_k_async(k0 + 64);
            load_v(k0 + 64);
        }

        if (compute) {
            // ---- O += P V ; l += P 1  (Pl rows wave-local) ----
#pragma unroll
            for (int kk = 0; kk < 2; kk++) {
                f16x8 pf[2];
#pragma unroll
                for (int im = 0; im < 2; im++)
                    pf[im] = *(const f16x8*)&Pl[swz(wave * 32 + im * 16 + l16, kk * 32 + quad * 8, 6)];
#pragma unroll
                for (int im = 0; im < 2; im++)
                    lacc[im] = __builtin_amdgcn_mfma_f32_16x16x32_f16(pf[im], ones, lacc[im], 0, 0, 0);
#pragma unroll
                for (int nt = 0; nt < 8; nt++) {
                    f16x8 vf = *(const f16x8*)&Vt[swz(nt * 16 + l16, kk * 32 + quad * 8, 6)];
#pragma unroll
                    for (int im = 0; im < 2; im++)
                        oacc[im][nt] = __builtin_amdgcn_mfma_f32_16x16x32_f16(pf[im], vf, oacc[im][nt], 0, 0, 0);
                }
            }
        }
    }

    // ---- epilogue: O /= l ----
#pragma unroll
    for (int im = 0; im < 2; im++) {
        int qrow = q0 + wave * 32 + im * 16 + quad * 4;
#pragma unroll
        for (int r = 0; r < 4; r++) {
            float inv = 1.0f / lacc[im][r];
#pragma unroll
            for (int nt = 0; nt < 8; nt++)
                O[bo + (long)(qrow + r) * Dc + nt * 16 + l16] = (f16)(oacc[im][nt][r] * inv);
        }
    }
}

// ---------------- launch ----------------
extern "C" void kernel_launch(void* const* d_in, const int* in_sizes, int n_in,
                              void* d_out, int out_size, void* d_ws, size_t ws_size,
                              hipStream_t stream)
{
    const float* x  = (const float*)d_in[0];
    const float* wq = (const float*)d_in[1];
    const float* wk = (const float*)d_in[2];
    const float* wv = (const float*)d_in[3];
    const float* wo = (const float*)d_in[4];
    const int*  pos = (const int*)d_in[5];
    float* out = (float*)d_out;

    const long E  = (long)Bc * Sc * Dc;        // 16.8M
    const long W  = (long)Dc * Dc;             // 4.2M
    const long EQ = (long)Bc * Sc * LDq;       // 50.3M (fused QKV)
    f16* ws   = (f16*)d_ws;
    f16* xh   = ws;
    f16* wqh  = ws + E;                        // wq,wk,wv contiguous -> W_qkv
    f16* wkh  = wqh + W;
    f16* wvh  = wkh + W;
    f16* woh  = wvh + W;
    f16* QKV  = woh + W;                       // [M][6144]
    float2* tab = (float2*)(QKV + EQ);         // 2048 x 64 cos/sin pairs (1 MB)
    f16* Oh   = xh;  // alias: xh dead after QKV projection

    cast_all_kernel<<<dim3(16384), 256, 0, stream>>>(x, wq, wk, wv, wo,
                                                     xh, wqh, wkh, wvh, woh);
    gen_rope_tab<<<dim3(Sc), 64, 0, stream>>>(pos, tab);

    // fused QKV projection + rope epilogue: C = [8192][6144]
    dim3 gq((Bc * Sc / 256) * (3 * Dc / 256));  // 32*24 = 768 blocks
    gemm_bt8<f16, true><<<gq, 512, 0, stream>>>(xh, wqh, QKV, tab,
                                                Bc * Sc, 3 * Dc, Dc);

    attn_kernel<<<dim3(1024), 256, 0, stream>>>(QKV, QKV + Dc, QKV + 2 * Dc, Oh);

    dim3 gg((Bc * Sc / 256) * (Dc / 256));      // 256 blocks
    gemm_bt8<float, false><<<gg, 512, 0, stream>>>(Oh, woh, out, nullptr,
                                                   Bc * Sc, Dc, Dc);
}

// Round 6
// 612.282 us; speedup vs baseline: 1.6884x; 1.0096x over previous
//
#include <hip/hip_runtime.h>
#include <cstdint>

typedef _Float16 f16;
typedef __attribute__((ext_vector_type(8))) _Float16 f16x8;
typedef __attribute__((ext_vector_type(4))) float f32x4;

constexpr int Bc  = 4;
constexpr int Sc  = 2048;
constexpr int Dc  = 2048;
constexpr int Hc  = 16;
constexpr int HDc = 128;
constexpr long Ec = (long)Bc * Sc * Dc;   // 16.8M elems per activation tensor

// ---------------- fused fp32 -> fp16 cast (all 5 tensors, 1 launch) ----------------
__global__ void cast_all_kernel(const float* __restrict__ x,  const float* __restrict__ wq,
                                const float* __restrict__ wk, const float* __restrict__ wv,
                                const float* __restrict__ wo,
                                f16* __restrict__ xh,  f16* __restrict__ wqh,
                                f16* __restrict__ wkh, f16* __restrict__ wvh,
                                f16* __restrict__ woh)
{
    long bid = blockIdx.x;
    const float* src; f16* dst; long off;
    if (bid < 8192)       { src = x;  dst = xh;  off = bid * 2048; }
    else {
        int r = (int)((bid - 8192) >> 11);
        off = ((bid - 8192) & 2047) * 2048;
        switch (r) {
            case 0:  src = wq; dst = wqh; break;
            case 1:  src = wk; dst = wkh; break;
            case 2:  src = wv; dst = wvh; break;
            default: src = wo; dst = woh; break;
        }
    }
    long i = off + (long)threadIdx.x * 8;
    float4 a = *(const float4*)(src + i);
    float4 b = *(const float4*)(src + i + 4);
    f16x8 o = { (f16)a.x, (f16)a.y, (f16)a.z, (f16)a.w,
                (f16)b.x, (f16)b.y, (f16)b.z, (f16)b.w };
    *(f16x8*)(dst + i) = o;
}

// ---------------- RoPE cos/sin table (S x 64 pairs, 1 MB) ----------------
__global__ void gen_rope_tab(const int* __restrict__ pos, float2* __restrict__ tab)
{
    int s = blockIdx.x, i = threadIdx.x;
    float inv = expf(-(float)i * (9.210340371976184f / 64.0f));
    float ang = (float)pos[s] * inv;
    float sn, cs;
    sincosf(ang, &sn, &cs);
    tab[s * 64 + i] = make_float2(cs, sn);
}

// ---------------- async global->LDS 16B/lane ----------------
__device__ __forceinline__ void async_cp16(const f16* g, f16* l)
{
    __builtin_amdgcn_global_load_lds(
        (__attribute__((address_space(1))) void*)(g),
        (__attribute__((address_space(3))) void*)(l), 16, 0, 0);
}

// ---------------- GEMM: C[m,n] = sum_k A[m,k] * W[n,k] ----------------
// 256x256 tile, 512 threads (8 waves, 2M x 4N), BK=32, ring of 4 LDS K-slots.
// R5: staging deepened to t+3 (ring-4 WAR-safe: slot (kt+3)&3 = slot (kt-1)&3,
// reads retired before tile-(kt-1) end barrier), tile-end wait vmcnt(8)
// (tiles t+2,t+3 in flight = 8 loads/wave; t+1 landed). Rationale: B panels
// (25MB/sweep) miss 4MB L2 -> staged loads return at L3/HBM latency; t+2
// depth (~560cyc) didn't cover it, t+3 (~1us) does.
// ROPE=true: N=6144 fused QKV; epilogue applies rotary to regions 0,1 (Q,K)
// via __shfl_xor(v,1) pair exchange + cos/sin table, and writes each region
// to a DENSE [M][2048] buffer at C + region*Ec (R4 lesson: 6144-stride K/V
// cost attn +85us).
template<typename OUT_T, bool ROPE>
__global__ __launch_bounds__(512, 2) void gemm_bt8(
    const f16* __restrict__ A, const f16* __restrict__ W,
    OUT_T* __restrict__ C, const float2* __restrict__ tab,
    int M, int N, int K)
{
    __shared__ alignas(16) f16 As[4][8192];   // [slot][256 rows x 32 cols]
    __shared__ alignas(16) f16 Bs[4][8192];

    const int tid  = threadIdx.x;
    const int wave = tid >> 6, lane = tid & 63;
    const int l16  = lane & 15, quad = lane >> 4;
    const int wm   = wave >> 2, wn = wave & 3;

    // XCD-bijective block swizzle (nwg % 8 == 0 for all our grids)
    const int nwg = (int)gridDim.x;
    int bid = (int)blockIdx.x;
    int wg  = ((nwg & 7) == 0) ? ((bid & 7) * (nwg >> 3) + (bid >> 3)) : bid;
    const int ntile = N >> 8;
    const int mt = wg / ntile, nt = wg % ntile;
    const int m0 = mt << 8, n0 = nt << 8;

    // ---- staging addresses (thread t covers phys row=t>>2, chunk=t&3) ----
    const int  prow = tid >> 2;                               // 0..127
    const int  lch  = (((tid & 3) ^ ((prow >> 1) & 3)) << 3); // logical f16 col
    const f16* Asrc = A + (long)(m0 + prow) * K + lch;
    const f16* Bsrc = W + (long)(n0 + prow) * K + lch;
    const long rsk  = (long)K << 7;           // +128 rows
    const int  dst0 = wave << 9;              // wave-uniform LDS base (f16)

    const int nkt = K >> 5;

    auto stA = [&](int kt) {
        const f16* g = Asrc + ((long)kt << 5);
        int s = kt & 3;
        async_cp16(g,       &As[s][dst0]);
        async_cp16(g + rsk, &As[s][4096 + dst0]);
    };
    auto stB = [&](int kt) {
        const f16* g = Bsrc + ((long)kt << 5);
        int s = kt & 3;
        async_cp16(g,       &Bs[s][dst0]);
        async_cp16(g + rsk, &Bs[s][4096 + dst0]);
    };

    // ---- fragment read addressing (swizzled chunk is lane-constant) ----
    const int coff = ((quad ^ ((l16 >> 1) & 3)) << 3);
    const int arow = wm * 128 + l16;          // + i*16
    const int brow = wn * 64  + l16;          // + j*16

    f32x4 acc[8][4];
#pragma unroll
    for (int i = 0; i < 8; i++)
#pragma unroll
        for (int j = 0; j < 4; j++) acc[i][j] = (f32x4){0.f, 0.f, 0.f, 0.f};

    // ---- prologue: stage tiles 0,1,2 (12 loads/wave); wait tile 0 (8 left) ----
    stA(0); stB(0);
    if (nkt > 1) { stA(1); stB(1); }
    if (nkt > 2) { stA(2); stB(2); }
    if (nkt > 2)      asm volatile("s_waitcnt vmcnt(8)" ::: "memory");
    else if (nkt > 1) asm volatile("s_waitcnt vmcnt(4)" ::: "memory");
    else              asm volatile("s_waitcnt vmcnt(0)" ::: "memory");
    __builtin_amdgcn_s_barrier();
    __builtin_amdgcn_sched_barrier(0);

    for (int kt = 0; kt < nkt; ++kt) {
        const int s = kt & 3;
        const f16* as = &As[s][(long)arow * 32 + coff];
        const f16* bs = &Bs[s][(long)brow * 32 + coff];

        // ---- phase 1: B all + A low-half, stage A(t+3), MFMA quadrant 0 ----
        f16x8 bfr[4], afr[4];
#pragma unroll
        for (int j = 0; j < 4; ++j) bfr[j] = *(const f16x8*)(bs + j * 512);
#pragma unroll
        for (int i = 0; i < 4; ++i) afr[i] = *(const f16x8*)(as + i * 512);
        if (kt + 3 < nkt) stA(kt + 3);
        asm volatile("s_waitcnt lgkmcnt(0)" ::: "memory");
        __builtin_amdgcn_sched_barrier(0);
        __builtin_amdgcn_s_setprio(1);
#pragma unroll
        for (int i = 0; i < 4; ++i)
#pragma unroll
            for (int j = 0; j < 4; ++j)
                acc[i][j] = __builtin_amdgcn_mfma_f32_16x16x32_f16(afr[i], bfr[j], acc[i][j], 0, 0, 0);
        __builtin_amdgcn_s_setprio(0);

        // ---- phase 2: A high-half, stage B(t+3), MFMA quadrant 1 ----
        f16x8 afr2[4];
#pragma unroll
        for (int i = 0; i < 4; ++i) afr2[i] = *(const f16x8*)(as + (i + 4) * 512);
        if (kt + 3 < nkt) stB(kt + 3);
        asm volatile("s_waitcnt lgkmcnt(0)" ::: "memory");
        __builtin_amdgcn_sched_barrier(0);
        __builtin_amdgcn_s_setprio(1);
#pragma unroll
        for (int i = 0; i < 4; ++i)
#pragma unroll
            for (int j = 0; j < 4; ++j)
                acc[i + 4][j] = __builtin_amdgcn_mfma_f32_16x16x32_f16(afr2[i], bfr[j], acc[i + 4][j], 0, 0, 0);
        __builtin_amdgcn_s_setprio(0);

        // ---- tile boundary: counted wait (t+1 landed; t+2,t+3 in flight) ----
        if (kt + 3 < nkt)      asm volatile("s_waitcnt vmcnt(8)" ::: "memory");
        else if (kt + 2 < nkt) asm volatile("s_waitcnt vmcnt(4)" ::: "memory");
        else if (kt + 1 < nkt) asm volatile("s_waitcnt vmcnt(0)" ::: "memory");
        __builtin_amdgcn_s_barrier();
        __builtin_amdgcn_sched_barrier(0);
    }

    // ---- epilogue (optionally fused RoPE + region split on f32 acc) ----
#pragma unroll
    for (int i = 0; i < 8; ++i) {
        int row = m0 + wm * 128 + i * 16 + quad * 4;
#pragma unroll
        for (int j = 0; j < 4; ++j) {
            int col = n0 + wn * 64 + j * 16 + l16;
            if (ROPE) {
                // region 0/1/2 = Q/K/V, each written dense [M][2048]
                const int  reg  = col >> 11;           // block-uniform
                const int  coll = col & 2047;
                OUT_T* Co = C + (long)reg * Ec;
                if (reg < 2) {                         // rotary on Q,K
                    const int  ip = (coll & 127) >> 1;
                    const bool ev = !(coll & 1);
#pragma unroll
                    for (int r = 0; r < 4; ++r) {
                        float v = acc[i][j][r];
                        float p = __shfl_xor(v, 1, 64);
                        int   sfx = (row + r) & (Sc - 1);
                        float2 cs = tab[sfx * 64 + ip];
                        float o = ev ? (v * cs.x - p * cs.y) : (p * cs.y + v * cs.x);
                        Co[(long)(row + r) * 2048 + coll] = (OUT_T)o;
                    }
                } else {
#pragma unroll
                    for (int r = 0; r < 4; ++r)
                        Co[(long)(row + r) * 2048 + coll] = (OUT_T)acc[i][j][r];
                }
            } else {
#pragma unroll
                for (int r = 0; r < 4; ++r)
                    C[(long)(row + r) * N + col] = (OUT_T)acc[i][j][r];
            }
        }
    }
}

// ---------------- Flash attention v6 (causal) — R3 version, dense strides ----------------
// A(drain: Kt=K[kt], vreg=V[kt]) -> write Vt -> B -> QK^T -> softmax->Pl ->
// C(Kt reads retired) -> issue K-DMA[kt+1]+load_v[kt+1] (hidden under PV) -> PV.
// 48K LDS, launch_bounds(256,2) (R2 lesson: bound=3 -> VGPR clamp -> spill).
__device__ __forceinline__ int swz(int row, int col, int ldshift) {
    return (row << ldshift) + (((((col >> 3) ^ ((row >> 1) & 7)) << 3) | (col & 7)));
}

__global__ __launch_bounds__(256, 2) void attn_kernel(
    const f16* __restrict__ Q, const f16* __restrict__ Kg,
    const f16* __restrict__ Vg, f16* __restrict__ O)
{
    __shared__ alignas(16) f16 Kt[64 * 128];
    __shared__ alignas(16) f16 Vt[128 * 64];
    __shared__ alignas(16) f16 Pl[128 * 64];

    const int tid  = threadIdx.x;
    const int wave = tid >> 6, lane = tid & 63;
    const int l16  = lane & 15, quad = lane >> 4;

    const int L  = (int)blockIdx.x;
    const int bh = (L & 7) + 8 * (L >> 7);
    const int qi = 15 - ((L >> 3) & 15);
    const int b  = bh >> 4, h = bh & 15;
    const long base = (long)b * Sc * Dc + (long)h * HDc;
    const float cexp = 0.12751742366f;  // log2(e)/sqrt(128)

    long koff[4];
    f16* kdst[4];
#pragma unroll
    for (int j = 0; j < 4; j++) {
        int row_l = j * 16 + wave * 4 + (lane >> 4);
        int chg   = (lane & 15) ^ ((row_l >> 1) & 7);
        koff[j]   = base + (long)row_l * Dc + chg * 8;
        kdst[j]   = (f16*)&Kt[(j * 16 + wave * 4) * 128];
    }
    const int vd0 = lane * 2;

    f16x8 ones;
#pragma unroll
    for (int i = 0; i < 8; i++) ones[i] = (f16)1.0f;

    unsigned int vreg[2][8];
    auto load_v = [&](int k0) {
#pragma unroll
        for (int j = 0; j < 2; j++) {
            int kk0 = wave * 8 + j * 32;
#pragma unroll
            for (int i2 = 0; i2 < 8; i2++)
                vreg[j][i2] = *(const unsigned int*)&Vg[base + (long)(k0 + kk0 + i2) * Dc + vd0];
        }
    };
    auto load_k_async = [&](int k0) {
#pragma unroll
        for (int j = 0; j < 4; j++)
            async_cp16(Kg + koff[j] + (long)k0 * Dc, kdst[j]);
    };

    const int q0  = qi * 128;
    const int nkt = 2 * qi + 2;
    const int rlo = q0 + wave * 32;

    f16x8 qf[2][4];
#pragma unroll
    for (int im = 0; im < 2; im++)
#pragma unroll
        for (int kk = 0; kk < 4; kk++)
            qf[im][kk] = *(const f16x8*)&Q[base + (long)(q0 + wave * 32 + im * 16 + l16) * Dc
                                           + kk * 32 + quad * 8];

    f32x4 oacc[2][8];
    f32x4 lacc[2];
#pragma unroll
    for (int im = 0; im < 2; im++) {
        lacc[im] = (f32x4){0.f, 0.f, 0.f, 0.f};
#pragma unroll
        for (int nt = 0; nt < 8; nt++) oacc[im][nt] = (f32x4){0.f, 0.f, 0.f, 0.f};
    }

    load_k_async(0);
    load_v(0);
    for (int kt = 0; kt < nkt; kt++) {
        const int k0 = kt * 64;
        __syncthreads();   // A: vmcnt drained -> K[kt] in Kt, vreg = V[kt]; prev LDS reads done
        // ---- write V tile (register transpose) ----
#pragma unroll
        for (int j = 0; j < 2; j++) {
            int kk0 = wave * 8 + j * 32;
            f16x8 lo, hi;
#pragma unroll
            for (int i2 = 0; i2 < 8; i2++) {
                lo[i2] = ((const f16*)&vreg[j][i2])[0];
                hi[i2] = ((const f16*)&vreg[j][i2])[1];
            }
            *(f16x8*)&Vt[swz(vd0,     kk0, 6)] = lo;
            *(f16x8*)&Vt[swz(vd0 + 1, kk0, 6)] = hi;
        }
        __syncthreads();   // B: Vt visible

        const bool compute = (k0 <= rlo + 31);   // wave-uniform causal skip
        if (compute) {
            // ---- S = Q K^T ----
            f32x4 sf[2][4];
#pragma unroll
            for (int im = 0; im < 2; im++)
#pragma unroll
                for (int in = 0; in < 4; in++) sf[im][in] = (f32x4){0.f, 0.f, 0.f, 0.f};
#pragma unroll
            for (int kk = 0; kk < 4; kk++) {
                f16x8 bf[4];
#pragma unroll
                for (int in = 0; in < 4; in++)
                    bf[in] = *(const f16x8*)&Kt[swz(in * 16 + l16, kk * 32 + quad * 8, 7)];
#pragma unroll
                for (int im = 0; im < 2; im++)
#pragma unroll
                    for (int in = 0; in < 4; in++)
                        sf[im][in] = __builtin_amdgcn_mfma_f32_16x16x32_f16(qf[im][kk], bf[in], sf[im][in], 0, 0, 0);
            }

            // ---- softmax -> Pl (consumes sf BEFORE barrier C: short liveness) ----
#pragma unroll
            for (int im = 0; im < 2; im++) {
                const int rbase = rlo + im * 16;
                const bool need_mask = (k0 + 63 > rbase);
#pragma unroll
                for (int in = 0; in < 4; in++) {
#pragma unroll
                    for (int r = 0; r < 4; r++) {
                        float p = __builtin_amdgcn_exp2f(sf[im][in][r] * cexp);
                        if (need_mask) {
                            int kc  = k0 + in * 16 + l16;
                            int row = rbase + quad * 4 + r;
                            p = (kc <= row) ? p : 0.f;
                        }
                        Pl[swz(wave * 32 + im * 16 + quad * 4 + r, in * 16 + l16, 6)] = (f16)p;
                    }
                }
            }
        }
        __syncthreads();   // C: all waves' Kt reads retired -> safe to overwrite Kt

        // ---- prefetch next tile (hidden under PV, waited at next A) ----
        if (kt + 1 < nkt) {
            load_k_async(k0 + 64);
            load_v(k0 + 64);
        }

        if (compute) {
            // ---- O += P V ; l += P 1  (Pl rows wave-local) ----
#pragma unroll
            for (int kk = 0; kk < 2; kk++) {
                f16x8 pf[2];
#pragma unroll
                for (int im = 0; im < 2; im++)
                    pf[im] = *(const f16x8*)&Pl[swz(wave * 32 + im * 16 + l16, kk * 32 + quad * 8, 6)];
#pragma unroll
                for (int im = 0; im < 2; im++)
                    lacc[im] = __builtin_amdgcn_mfma_f32_16x16x32_f16(pf[im], ones, lacc[im], 0, 0, 0);
#pragma unroll
                for (int nt = 0; nt < 8; nt++) {
                    f16x8 vf = *(const f16x8*)&Vt[swz(nt * 16 + l16, kk * 32 + quad * 8, 6)];
#pragma unroll
                    for (int im = 0; im < 2; im++)
                        oacc[im][nt] = __builtin_amdgcn_mfma_f32_16x16x32_f16(pf[im], vf, oacc[im][nt], 0, 0, 0);
                }
            }
        }
    }

    // ---- epilogue: O /= l ----
#pragma unroll
    for (int im = 0; im < 2; im++) {
        int qrow = q0 + wave * 32 + im * 16 + quad * 4;
#pragma unroll
        for (int r = 0; r < 4; r++) {
            float inv = 1.0f / lacc[im][r];
#pragma unroll
            for (int nt = 0; nt < 8; nt++)
                O[base + (long)(qrow + r) * Dc + nt * 16 + l16] = (f16)(oacc[im][nt][r] * inv);
        }
    }
}

// ---------------- launch ----------------
extern "C" void kernel_launch(void* const* d_in, const int* in_sizes, int n_in,
                              void* d_out, int out_size, void* d_ws, size_t ws_size,
                              hipStream_t stream)
{
    const float* x  = (const float*)d_in[0];
    const float* wq = (const float*)d_in[1];
    const float* wk = (const float*)d_in[2];
    const float* wv = (const float*)d_in[3];
    const float* wo = (const float*)d_in[4];
    const int*  pos = (const int*)d_in[5];
    float* out = (float*)d_out;

    const long W  = (long)Dc * Dc;             // 4.2M
    f16* ws   = (f16*)d_ws;
    f16* xh   = ws;
    f16* wqh  = ws + Ec;                       // wq,wk,wv contiguous -> W_qkv
    f16* wkh  = wqh + W;
    f16* wvh  = wkh + W;
    f16* woh  = wvh + W;
    f16* Qh   = woh + W;                       // dense [M][2048] each
    f16* Kh   = Qh + Ec;
    f16* Vh   = Kh + Ec;
    float2* tab = (float2*)(Vh + Ec);          // 2048 x 64 cos/sin pairs (1 MB)
    f16* Oh   = xh;  // alias: xh dead after QKV projection

    cast_all_kernel<<<dim3(16384), 256, 0, stream>>>(x, wq, wk, wv, wo,
                                                     xh, wqh, wkh, wvh, woh);
    gen_rope_tab<<<dim3(Sc), 64, 0, stream>>>(pos, tab);

    // fused QKV projection + rope epilogue, region-split dense outputs
    dim3 gq((Bc * Sc / 256) * (3 * Dc / 256));  // 32*24 = 768 blocks
    gemm_bt8<f16, true><<<gq, 512, 0, stream>>>(xh, wqh, Qh, tab,
                                                Bc * Sc, 3 * Dc, Dc);

    attn_kernel<<<dim3(1024), 256, 0, stream>>>(Qh, Kh, Vh, Oh);

    dim3 gg((Bc * Sc / 256) * (Dc / 256));      // 256 blocks
    gemm_bt8<float, false><<<gg, 512, 0, stream>>>(Oh, woh, out, nullptr,
                                                   Bc * Sc, Dc, Dc);
}

// Round 7
// 552.849 us; speedup vs baseline: 1.8699x; 1.1075x over previous
//
#include <hip/hip_runtime.h>
#include <cstdint>

typedef _Float16 f16;
typedef __attribute__((ext_vector_type(8))) _Float16 f16x8;
typedef __attribute__((ext_vector_type(4))) float f32x4;

constexpr int Bc  = 4;
constexpr int Sc  = 2048;
constexpr int Dc  = 2048;
constexpr int Hc  = 16;
constexpr int HDc = 128;
constexpr long Ec = (long)Bc * Sc * Dc;   // 16.8M elems per activation tensor

// ---------------- fused fp32 -> fp16 cast (all 5 tensors, 1 launch) ----------------
__global__ void cast_all_kernel(const float* __restrict__ x,  const float* __restrict__ wq,
                                const float* __restrict__ wk, const float* __restrict__ wv,
                                const float* __restrict__ wo,
                                f16* __restrict__ xh,  f16* __restrict__ wqh,
                                f16* __restrict__ wkh, f16* __restrict__ wvh,
                                f16* __restrict__ woh)
{
    long bid = blockIdx.x;
    const float* src; f16* dst; long off;
    if (bid < 8192)       { src = x;  dst = xh;  off = bid * 2048; }
    else {
        int r = (int)((bid - 8192) >> 11);
        off = ((bid - 8192) & 2047) * 2048;
        switch (r) {
            case 0:  src = wq; dst = wqh; break;
            case 1:  src = wk; dst = wkh; break;
            case 2:  src = wv; dst = wvh; break;
            default: src = wo; dst = woh; break;
        }
    }
    long i = off + (long)threadIdx.x * 8;
    float4 a = *(const float4*)(src + i);
    float4 b = *(const float4*)(src + i + 4);
    f16x8 o = { (f16)a.x, (f16)a.y, (f16)a.z, (f16)a.w,
                (f16)b.x, (f16)b.y, (f16)b.z, (f16)b.w };
    *(f16x8*)(dst + i) = o;
}

// ---------------- RoPE cos/sin table (S x 64 pairs, 1 MB) ----------------
__global__ void gen_rope_tab(const int* __restrict__ pos, float2* __restrict__ tab)
{
    int s = blockIdx.x, i = threadIdx.x;
    float inv = expf(-(float)i * (9.210340371976184f / 64.0f));
    float ang = (float)pos[s] * inv;
    float sn, cs;
    sincosf(ang, &sn, &cs);
    tab[s * 64 + i] = make_float2(cs, sn);
}

// ---------------- async global->LDS 16B/lane ----------------
__device__ __forceinline__ void async_cp16(const f16* g, f16* l)
{
    __builtin_amdgcn_global_load_lds(
        (__attribute__((address_space(1))) void*)(g),
        (__attribute__((address_space(3))) void*)(l), 16, 0, 0);
}

// ---------------- GEMM: C[m,n] = sum_k A[m,k] * W[n,k] ----------------
// 256x256 tile, 512 threads (8 waves, 2M x 4N), BK=32, ring of 4 LDS K-slots,
// staging t+3 deep, counted vmcnt(8) at tile end, no intra-tile barriers.
// R7: block-order L2-band swizzle. Evidence: FETCH_SIZE 366MB vs 58MB ideal
// (6x overfetch) at mt-major order -> one XCD's ~32 concurrent blocks span all
// 24 nt -> 24MB B working set thrashes 4MB L2. New order: within each XCD
// chunk, (mt,nt) visited in 4-wide nt bands -> concurrent set 4mt x 8nt =
// A 4MB + B 8MB. Bijective; falls back to old order if shapes don't divide.
template<typename OUT_T, bool ROPE>
__global__ __launch_bounds__(512, 2) void gemm_bt8(
    const f16* __restrict__ A, const f16* __restrict__ W,
    OUT_T* __restrict__ C, const float2* __restrict__ tab,
    int M, int N, int K)
{
    __shared__ alignas(16) f16 As[4][8192];   // [slot][256 rows x 32 cols]
    __shared__ alignas(16) f16 Bs[4][8192];

    const int tid  = threadIdx.x;
    const int wave = tid >> 6, lane = tid & 63;
    const int l16  = lane & 15, quad = lane >> 4;
    const int wm   = wave >> 2, wn = wave & 3;

    const int nwg = (int)gridDim.x;
    const int bid = (int)blockIdx.x;
    const int ntile = N >> 8;
    int mt, nt;
    if ((nwg & 7) == 0 && ((nwg >> 3) % ntile) == 0 && (ntile & 3) == 0) {
        const int cpx = nwg >> 3, mtspan = cpx / ntile;   // chunk covers mtspan m-panels x all nt
        const int c = bid & 7, local = bid >> 3;          // XCD chunk, pos within
        const int band = local / (4 * mtspan);
        const int rem  = local - band * (4 * mtspan);
        mt = c * mtspan + (rem >> 2);
        nt = (band << 2) + (rem & 3);
    } else {
        int wg = ((nwg & 7) == 0) ? ((bid & 7) * (nwg >> 3) + (bid >> 3)) : bid;
        mt = wg / ntile; nt = wg % ntile;
    }
    const int m0 = mt << 8, n0 = nt << 8;

    // ---- staging addresses (thread t covers phys row=t>>2, chunk=t&3) ----
    const int  prow = tid >> 2;                               // 0..127
    const int  lch  = (((tid & 3) ^ ((prow >> 1) & 3)) << 3); // logical f16 col
    const f16* Asrc = A + (long)(m0 + prow) * K + lch;
    const f16* Bsrc = W + (long)(n0 + prow) * K + lch;
    const long rsk  = (long)K << 7;           // +128 rows
    const int  dst0 = wave << 9;              // wave-uniform LDS base (f16)

    const int nkt = K >> 5;

    auto stA = [&](int kt) {
        const f16* g = Asrc + ((long)kt << 5);
        int s = kt & 3;
        async_cp16(g,       &As[s][dst0]);
        async_cp16(g + rsk, &As[s][4096 + dst0]);
    };
    auto stB = [&](int kt) {
        const f16* g = Bsrc + ((long)kt << 5);
        int s = kt & 3;
        async_cp16(g,       &Bs[s][dst0]);
        async_cp16(g + rsk, &Bs[s][4096 + dst0]);
    };

    // ---- fragment read addressing (swizzled chunk is lane-constant) ----
    const int coff = ((quad ^ ((l16 >> 1) & 3)) << 3);
    const int arow = wm * 128 + l16;          // + i*16
    const int brow = wn * 64  + l16;          // + j*16

    f32x4 acc[8][4];
#pragma unroll
    for (int i = 0; i < 8; i++)
#pragma unroll
        for (int j = 0; j < 4; j++) acc[i][j] = (f32x4){0.f, 0.f, 0.f, 0.f};

    // ---- prologue: stage tiles 0,1,2 (12 loads/wave); wait tile 0 (8 left) ----
    stA(0); stB(0);
    if (nkt > 1) { stA(1); stB(1); }
    if (nkt > 2) { stA(2); stB(2); }
    if (nkt > 2)      asm volatile("s_waitcnt vmcnt(8)" ::: "memory");
    else if (nkt > 1) asm volatile("s_waitcnt vmcnt(4)" ::: "memory");
    else              asm volatile("s_waitcnt vmcnt(0)" ::: "memory");
    __builtin_amdgcn_s_barrier();
    __builtin_amdgcn_sched_barrier(0);

    for (int kt = 0; kt < nkt; ++kt) {
        const int s = kt & 3;
        const f16* as = &As[s][(long)arow * 32 + coff];
        const f16* bs = &Bs[s][(long)brow * 32 + coff];

        // ---- phase 1: B all + A low-half, stage A(t+3), MFMA quadrant 0 ----
        f16x8 bfr[4], afr[4];
#pragma unroll
        for (int j = 0; j < 4; ++j) bfr[j] = *(const f16x8*)(bs + j * 512);
#pragma unroll
        for (int i = 0; i < 4; ++i) afr[i] = *(const f16x8*)(as + i * 512);
        if (kt + 3 < nkt) stA(kt + 3);
        asm volatile("s_waitcnt lgkmcnt(0)" ::: "memory");
        __builtin_amdgcn_sched_barrier(0);
        __builtin_amdgcn_s_setprio(1);
#pragma unroll
        for (int i = 0; i < 4; ++i)
#pragma unroll
            for (int j = 0; j < 4; ++j)
                acc[i][j] = __builtin_amdgcn_mfma_f32_16x16x32_f16(afr[i], bfr[j], acc[i][j], 0, 0, 0);
        __builtin_amdgcn_s_setprio(0);

        // ---- phase 2: A high-half, stage B(t+3), MFMA quadrant 1 ----
        f16x8 afr2[4];
#pragma unroll
        for (int i = 0; i < 4; ++i) afr2[i] = *(const f16x8*)(as + (i + 4) * 512);
        if (kt + 3 < nkt) stB(kt + 3);
        asm volatile("s_waitcnt lgkmcnt(0)" ::: "memory");
        __builtin_amdgcn_sched_barrier(0);
        __builtin_amdgcn_s_setprio(1);
#pragma unroll
        for (int i = 0; i < 4; ++i)
#pragma unroll
            for (int j = 0; j < 4; ++j)
                acc[i + 4][j] = __builtin_amdgcn_mfma_f32_16x16x32_f16(afr2[i], bfr[j], acc[i + 4][j], 0, 0, 0);
        __builtin_amdgcn_s_setprio(0);

        // ---- tile boundary: counted wait (t+1 landed; t+2,t+3 in flight) ----
        if (kt + 3 < nkt)      asm volatile("s_waitcnt vmcnt(8)" ::: "memory");
        else if (kt + 2 < nkt) asm volatile("s_waitcnt vmcnt(4)" ::: "memory");
        else if (kt + 1 < nkt) asm volatile("s_waitcnt vmcnt(0)" ::: "memory");
        __builtin_amdgcn_s_barrier();
        __builtin_amdgcn_sched_barrier(0);
    }

    // ---- epilogue (optionally fused RoPE + region split on f32 acc) ----
#pragma unroll
    for (int i = 0; i < 8; ++i) {
        int row = m0 + wm * 128 + i * 16 + quad * 4;
#pragma unroll
        for (int j = 0; j < 4; ++j) {
            int col = n0 + wn * 64 + j * 16 + l16;
            if (ROPE) {
                // region 0/1/2 = Q/K/V, each written dense [M][2048]
                const int  reg  = col >> 11;           // block-uniform
                const int  coll = col & 2047;
                OUT_T* Co = C + (long)reg * Ec;
                if (reg < 2) {                         // rotary on Q,K
                    const int  ip = (coll & 127) >> 1;
                    const bool ev = !(coll & 1);
#pragma unroll
                    for (int r = 0; r < 4; ++r) {
                        float v = acc[i][j][r];
                        float p = __shfl_xor(v, 1, 64);
                        int   sfx = (row + r) & (Sc - 1);
                        float2 cs = tab[sfx * 64 + ip];
                        float o = ev ? (v * cs.x - p * cs.y) : (p * cs.y + v * cs.x);
                        Co[(long)(row + r) * 2048 + coll] = (OUT_T)o;
                    }
                } else {
#pragma unroll
                    for (int r = 0; r < 4; ++r)
                        Co[(long)(row + r) * 2048 + coll] = (OUT_T)acc[i][j][r];
                }
            } else {
#pragma unroll
                for (int r = 0; r < 4; ++r)
                    C[(long)(row + r) * N + col] = (OUT_T)acc[i][j][r];
            }
        }
    }
}

// ---------------- Flash attention v7 (causal) ----------------
// R7 changes vs v6:
// (1) Global LPT dispatch: qi = 15-(L>>6), bh = L&63 -> ALL 64 heaviest
//     (qi=15) blocks dispatch first; small blocks backfill. Previous order
//     started bh48-63's qi=15 blocks at L>=768 (second occupancy wave) ->
//     ~30us tail. XCD/KV locality preserved: bh&7 == L&7 still.
// (2) Barrier merge: "Vt visible" barrier dropped -- Vt writes only need to
//     complete before PV (cross-wave k-slices), not QK^T (reads Kt only).
//     Barrier C now serves both "Kt reads retired" and "Vt visible".
//     2 barriers/tile (was 3); V-transpose LDS writes overlap QK^T MFMA.
// Per-tile: A(drain: Kt=K[kt], vreg=V[kt]) -> V-write -> QK^T -> softmax->Pl
//           -> C -> issue K-DMA[kt+1]+load_v[kt+1] (hidden under PV) -> PV.
__device__ __forceinline__ int swz(int row, int col, int ldshift) {
    return (row << ldshift) + (((((col >> 3) ^ ((row >> 1) & 7)) << 3) | (col & 7)));
}

__global__ __launch_bounds__(256, 2) void attn_kernel(
    const f16* __restrict__ Q, const f16* __restrict__ Kg,
    const f16* __restrict__ Vg, f16* __restrict__ O)
{
    __shared__ alignas(16) f16 Kt[64 * 128];
    __shared__ alignas(16) f16 Vt[128 * 64];
    __shared__ alignas(16) f16 Pl[128 * 64];

    const int tid  = threadIdx.x;
    const int wave = tid >> 6, lane = tid & 63;
    const int l16  = lane & 15, quad = lane >> 4;

    const int L  = (int)blockIdx.x;
    const int bh = L & 63;                    // bh&7 == L&7: XCD-stable
    const int qi = 15 - ((L >> 6) & 15);      // global heavy-first
    const int b  = bh >> 4, h = bh & 15;
    const long base = (long)b * Sc * Dc + (long)h * HDc;
    const float cexp = 0.12751742366f;  // log2(e)/sqrt(128)

    long koff[4];
    f16* kdst[4];
#pragma unroll
    for (int j = 0; j < 4; j++) {
        int row_l = j * 16 + wave * 4 + (lane >> 4);
        int chg   = (lane & 15) ^ ((row_l >> 1) & 7);
        koff[j]   = base + (long)row_l * Dc + chg * 8;
        kdst[j]   = (f16*)&Kt[(j * 16 + wave * 4) * 128];
    }
    const int vd0 = lane * 2;

    f16x8 ones;
#pragma unroll
    for (int i = 0; i < 8; i++) ones[i] = (f16)1.0f;

    unsigned int vreg[2][8];
    auto load_v = [&](int k0) {
#pragma unroll
        for (int j = 0; j < 2; j++) {
            int kk0 = wave * 8 + j * 32;
#pragma unroll
            for (int i2 = 0; i2 < 8; i2++)
                vreg[j][i2] = *(const unsigned int*)&Vg[base + (long)(k0 + kk0 + i2) * Dc + vd0];
        }
    };
    auto load_k_async = [&](int k0) {
#pragma unroll
        for (int j = 0; j < 4; j++)
            async_cp16(Kg + koff[j] + (long)k0 * Dc, kdst[j]);
    };

    const int q0  = qi * 128;
    const int nkt = 2 * qi + 2;
    const int rlo = q0 + wave * 32;

    f16x8 qf[2][4];
#pragma unroll
    for (int im = 0; im < 2; im++)
#pragma unroll
        for (int kk = 0; kk < 4; kk++)
            qf[im][kk] = *(const f16x8*)&Q[base + (long)(q0 + wave * 32 + im * 16 + l16) * Dc
                                           + kk * 32 + quad * 8];

    f32x4 oacc[2][8];
    f32x4 lacc[2];
#pragma unroll
    for (int im = 0; im < 2; im++) {
        lacc[im] = (f32x4){0.f, 0.f, 0.f, 0.f};
#pragma unroll
        for (int nt = 0; nt < 8; nt++) oacc[im][nt] = (f32x4){0.f, 0.f, 0.f, 0.f};
    }

    load_k_async(0);
    load_v(0);
    for (int kt = 0; kt < nkt; kt++) {
        const int k0 = kt * 64;
        __syncthreads();   // A: vmcnt drained -> K[kt] in Kt, vreg = V[kt]; prev LDS reads done
        // ---- write V tile (register transpose); overlaps QK^T below ----
#pragma unroll
        for (int j = 0; j < 2; j++) {
            int kk0 = wave * 8 + j * 32;
            f16x8 lo, hi;
#pragma unroll
            for (int i2 = 0; i2 < 8; i2++) {
                lo[i2] = ((const f16*)&vreg[j][i2])[0];
                hi[i2] = ((const f16*)&vreg[j][i2])[1];
            }
            *(f16x8*)&Vt[swz(vd0,     kk0, 6)] = lo;
            *(f16x8*)&Vt[swz(vd0 + 1, kk0, 6)] = hi;
        }

        const bool compute = (k0 <= rlo + 31);   // wave-uniform causal skip
        if (compute) {
            // ---- S = Q K^T (reads Kt only; Vt writes in flight) ----
            f32x4 sf[2][4];
#pragma unroll
            for (int im = 0; im < 2; im++)
#pragma unroll
                for (int in = 0; in < 4; in++) sf[im][in] = (f32x4){0.f, 0.f, 0.f, 0.f};
#pragma unroll
            for (int kk = 0; kk < 4; kk++) {
                f16x8 bf[4];
#pragma unroll
                for (int in = 0; in < 4; in++)
                    bf[in] = *(const f16x8*)&Kt[swz(in * 16 + l16, kk * 32 + quad * 8, 7)];
#pragma unroll
                for (int im = 0; im < 2; im++)
#pragma unroll
                    for (int in = 0; in < 4; in++)
                        sf[im][in] = __builtin_amdgcn_mfma_f32_16x16x32_f16(qf[im][kk], bf[in], sf[im][in], 0, 0, 0);
            }

            // ---- softmax -> Pl (consumes sf early: short liveness) ----
#pragma unroll
            for (int im = 0; im < 2; im++) {
                const int rbase = rlo + im * 16;
                const bool need_mask = (k0 + 63 > rbase);
#pragma unroll
                for (int in = 0; in < 4; in++) {
#pragma unroll
                    for (int r = 0; r < 4; r++) {
                        float p = __builtin_amdgcn_exp2f(sf[im][in][r] * cexp);
                        if (need_mask) {
                            int kc  = k0 + in * 16 + l16;
                            int row = rbase + quad * 4 + r;
                            p = (kc <= row) ? p : 0.f;
                        }
                        Pl[swz(wave * 32 + im * 16 + quad * 4 + r, in * 16 + l16, 6)] = (f16)p;
                    }
                }
            }
        }
        __syncthreads();   // C: Kt reads retired (safe to DMA) + Vt fully visible

        // ---- prefetch next tile (hidden under PV, waited at next A) ----
        if (kt + 1 < nkt) {
            load_k_async(k0 + 64);
            load_v(k0 + 64);
        }

        if (compute) {
            // ---- O += P V ; l += P 1  (Pl rows wave-local) ----
#pragma unroll
            for (int kk = 0; kk < 2; kk++) {
                f16x8 pf[2];
#pragma unroll
                for (int im = 0; im < 2; im++)
                    pf[im] = *(const f16x8*)&Pl[swz(wave * 32 + im * 16 + l16, kk * 32 + quad * 8, 6)];
#pragma unroll
                for (int im = 0; im < 2; im++)
                    lacc[im] = __builtin_amdgcn_mfma_f32_16x16x32_f16(pf[im], ones, lacc[im], 0, 0, 0);
#pragma unroll
                for (int nt = 0; nt < 8; nt++) {
                    f16x8 vf = *(const f16x8*)&Vt[swz(nt * 16 + l16, kk * 32 + quad * 8, 6)];
#pragma unroll
                    for (int im = 0; im < 2; im++)
                        oacc[im][nt] = __builtin_amdgcn_mfma_f32_16x16x32_f16(pf[im], vf, oacc[im][nt], 0, 0, 0);
                }
            }
        }
    }

    // ---- epilogue: O /= l ----
#pragma unroll
    for (int im = 0; im < 2; im++) {
        int qrow = q0 + wave * 32 + im * 16 + quad * 4;
#pragma unroll
        for (int r = 0; r < 4; r++) {
            float inv = 1.0f / lacc[im][r];
#pragma unroll
            for (int nt = 0; nt < 8; nt++)
                O[base + (long)(qrow + r) * Dc + nt * 16 + l16] = (f16)(oacc[im][nt][r] * inv);
        }
    }
}

// ---------------- launch ----------------
extern "C" void kernel_launch(void* const* d_in, const int* in_sizes, int n_in,
                              void* d_out, int out_size, void* d_ws, size_t ws_size,
                              hipStream_t stream)
{
    const float* x  = (const float*)d_in[0];
    const float* wq = (const float*)d_in[1];
    const float* wk = (const float*)d_in[2];
    const float* wv = (const float*)d_in[3];
    const float* wo = (const float*)d_in[4];
    const int*  pos = (const int*)d_in[5];
    float* out = (float*)d_out;

    const long W  = (long)Dc * Dc;             // 4.2M
    f16* ws   = (f16*)d_ws;
    f16* xh   = ws;
    f16* wqh  = ws + Ec;                       // wq,wk,wv contiguous -> W_qkv
    f16* wkh  = wqh + W;
    f16* wvh  = wkh + W;
    f16* woh  = wvh + W;
    f16* Qh   = woh + W;                       // dense [M][2048] each
    f16* Kh   = Qh + Ec;
    f16* Vh   = Kh + Ec;
    float2* tab = (float2*)(Vh + Ec);          // 2048 x 64 cos/sin pairs (1 MB)
    f16* Oh   = xh;  // alias: xh dead after QKV projection

    cast_all_kernel<<<dim3(16384), 256, 0, stream>>>(x, wq, wk, wv, wo,
                                                     xh, wqh, wkh, wvh, woh);
    gen_rope_tab<<<dim3(Sc), 64, 0, stream>>>(pos, tab);

    // fused QKV projection + rope epilogue, region-split dense outputs
    dim3 gq((Bc * Sc / 256) * (3 * Dc / 256));  // 32*24 = 768 blocks
    gemm_bt8<f16, true><<<gq, 512, 0, stream>>>(xh, wqh, Qh, tab,
                                                Bc * Sc, 3 * Dc, Dc);

    attn_kernel<<<dim3(1024), 256, 0, stream>>>(Qh, Kh, Vh, Oh);

    dim3 gg((Bc * Sc / 256) * (Dc / 256));      // 256 blocks
    gemm_bt8<float, false><<<gg, 512, 0, stream>>>(Oh, woh, out, nullptr,
                                                   Bc * Sc, Dc, Dc);
}